// Round 8
// baseline (765.606 us; speedup 1.0000x reference)
//
#include <hip/hip_runtime.h>
#include <cstdint>
#include <cstddef>

// BiRWKV (RWKV-6 bidirectional time-mix), B=4 T=1024 C=768 H=12 D=64 LORA=64.
// Round 8: gemm_mfma_big rebuilt: 64x64 wave tiles (4 waves/block), double-
// buffered LDS with one barrier per K-step (load->MFMA->write pipeline), and
// packed-fp16 token-shift mix (mu pre-converted to fp16). Scan/lora unchanged.

#define HH   12
#define DD   64
#define CC   768
#define TT   1024
#define BBB  4
#define LR   64
#define BT   (BBB*TT)
#define WSQ  (CC*CC)

typedef unsigned short u16;
typedef _Float16 f16x8 __attribute__((ext_vector_type(8)));  // 8 f16 (4 VGPRs)
typedef float f32x4 __attribute__((ext_vector_type(4)));     // MFMA accumulator

__device__ __forceinline__ u16 f2h(float f) {
    const _Float16 h = (_Float16)f;
    return __builtin_bit_cast(u16, h);
}
__device__ __forceinline__ float h2f(u16 h) {
    return (float)__builtin_bit_cast(_Float16, h);
}

// pad_mask dtype detect (bool bytes vs int32 vs float32).
__device__ __forceinline__ float mask_val(const void* mp, int idx) {
    const unsigned char* b = (const unsigned char*)mp;
    const int i0 = ((const int*)mp)[0];
    if (i0 == 0x3f800000) {
        return ((const float*)mp)[idx] != 0.f ? 1.f : 0.f;
    }
    if ((b[1] | b[2] | b[3]) == 0) {
        return ((const int*)mp)[idx] != 0 ? 1.f : 0.f;
    }
    return b[idx] ? 1.f : 0.f;
}

// ---------------- prepass: weight transpose-convert, x/mu convert ----------------
struct TP10 { const float* src[10]; };

__global__ __launch_bounds__(256)
void transpose_conv(TP10 tj, u16* __restrict__ dst)
{
    __shared__ float sh[32][33];
    const int j = blockIdx.z;
    const float* __restrict__ src = tj.src[j];
    u16* __restrict__ d = dst + (size_t)j * WSQ;
    const int n0 = blockIdx.x << 5, k0 = blockIdx.y << 5;
    const int tx = threadIdx.x & 31, ty = threadIdx.x >> 5;
    #pragma unroll
    for (int i = 0; i < 4; ++i)
        sh[ty + (i << 3)][tx] = src[(size_t)(k0 + ty + (i << 3)) * CC + n0 + tx];
    __syncthreads();
    #pragma unroll
    for (int i = 0; i < 4; ++i)
        d[(size_t)(n0 + ty + (i << 3)) * CC + k0 + tx] =
            f2h(sh[tx][ty + (i << 3)]);
}

__global__ __launch_bounds__(256)
void convert_x(const float* __restrict__ x, u16* __restrict__ xb)
{
    const size_t off = ((size_t)blockIdx.x * 256 + threadIdx.x) * 8;
    const float4 a = *reinterpret_cast<const float4*>(x + off);
    const float4 b = *reinterpret_cast<const float4*>(x + off + 4);
    uint4 w;
    w.x = (unsigned)f2h(a.x) | ((unsigned)f2h(a.y) << 16);
    w.y = (unsigned)f2h(a.z) | ((unsigned)f2h(a.w) << 16);
    w.z = (unsigned)f2h(b.x) | ((unsigned)f2h(b.y) << 16);
    w.w = (unsigned)f2h(b.z) | ((unsigned)f2h(b.w) << 16);
    *reinterpret_cast<uint4*>(xb + off) = w;
}

__global__ __launch_bounds__(256)
void convert_mu(const float* __restrict__ mu, u16* __restrict__ muh, int n)
{
    const int i = blockIdx.x * 256 + threadIdx.x;
    if (i < n) muh[i] = f2h(mu[i]);
}

// ---------------- fp16 MFMA GEMM: 128x128 tile, 4 waves (64x64 each), ----------
// ---------------- double-buffered LDS, packed-fp16 mix ------------------------
struct GB { const u16* Wt[4]; float* out[4]; const u16* mu[4]; int act[4]; };

__global__ __launch_bounds__(256, 2)
void gemm_mfma_big(GB p, const u16* __restrict__ Ab, const u16* __restrict__ xb,
                   const void* __restrict__ mask,
                   const int K, const int N, const int dir, const int mixA)
{
    const int j = blockIdx.z;
    const u16* __restrict__ Wt = p.Wt[j];
    float* __restrict__ out = p.out[j];
    const u16* __restrict__ muh = p.mu[j];
    const int act = p.act[j];

    __shared__ __align__(16) u16 Als[2][128][72];
    __shared__ __align__(16) u16 Bls[2][128][72];

    const int tid = threadIdx.x;
    const int rowbase = blockIdx.x << 7;
    const int colbase = blockIdx.y << 7;
    const int lane = tid & 63;
    const int wid = tid >> 6;            // 0..3
    const int wr = (wid >> 1) << 6;      // 0 / 64
    const int wc = (wid & 1) << 6;       // 0 / 64
    const int lm = lane & 15;
    const int lk = (lane >> 4) << 3;     // 0,8,16,24

    // staging geometry: 4 groups of (row, kq) per thread
    int srow[4], skq[4], sb[4], st[4], stp[4], sts[4];
    #pragma unroll
    for (int it = 0; it < 4; ++it) {
        const int g = tid + (it << 8);
        srow[it] = g >> 3;
        skq[it]  = (g & 7) << 3;
        const int s = rowbase + srow[it];
        sb[it] = s >> 10;
        const int ts = s & (TT - 1);
        sts[it] = ts;
        const int t = dir ? (TT - 1 - ts) : ts;
        st[it]  = t;
        stp[it] = dir ? (t + 1) : (t - 1);
    }

    uint4 aR[4], pR[4], mR[4], bR[4];

    auto LOAD = [&](int k0) {
        #pragma unroll
        for (int it = 0; it < 4; ++it) {
            bR[it] = *reinterpret_cast<const uint4*>(
                Wt + (size_t)(colbase + srow[it]) * K + k0 + skq[it]);
            if (mixA) {
                aR[it] = *reinterpret_cast<const uint4*>(
                    xb + (size_t)(sb[it] * TT + st[it]) * CC + k0 + skq[it]);
                pR[it] = make_uint4(0u, 0u, 0u, 0u);
                if (sts[it] > 0)
                    pR[it] = *reinterpret_cast<const uint4*>(
                        xb + (size_t)(sb[it] * TT + stp[it]) * CC + k0 + skq[it]);
                mR[it] = *reinterpret_cast<const uint4*>(muh + k0 + skq[it]);
            } else {
                aR[it] = *reinterpret_cast<const uint4*>(
                    Ab + (size_t)(rowbase + srow[it]) * K + k0 + skq[it]);
            }
        }
    };
    auto WRITE = [&](int buf) {
        #pragma unroll
        for (int it = 0; it < 4; ++it) {
            *reinterpret_cast<uint4*>(&Bls[buf][srow[it]][skq[it]]) = bR[it];
            if (mixA) {
                const f16x8 xa = __builtin_bit_cast(f16x8, aR[it]);
                const f16x8 xp = __builtin_bit_cast(f16x8, pR[it]);
                const f16x8 mm = __builtin_bit_cast(f16x8, mR[it]);
                const f16x8 res = (xp - xa) * mm + xa;   // v_pk_sub/v_pk_fma
                *reinterpret_cast<uint4*>(&Als[buf][srow[it]][skq[it]]) =
                    __builtin_bit_cast(uint4, res);
            } else {
                *reinterpret_cast<uint4*>(&Als[buf][srow[it]][skq[it]]) = aR[it];
            }
        }
    };

    f32x4 acc[4][4] = {};
    auto COMPUTE = [&](int buf) {
        #pragma unroll
        for (int ks = 0; ks < 2; ++ks) {
            const int ko = (ks << 5) + lk;
            f16x8 av[4], bv[4];
            #pragma unroll
            for (int mi = 0; mi < 4; ++mi)
                av[mi] = *reinterpret_cast<const f16x8*>(
                    &Als[buf][wr + mi * 16 + lm][ko]);
            #pragma unroll
            for (int ni = 0; ni < 4; ++ni)
                bv[ni] = *reinterpret_cast<const f16x8*>(
                    &Bls[buf][wc + ni * 16 + lm][ko]);
            #pragma unroll
            for (int mi = 0; mi < 4; ++mi)
                #pragma unroll
                for (int ni = 0; ni < 4; ++ni)
                    acc[mi][ni] = __builtin_amdgcn_mfma_f32_16x16x32_f16(
                        av[mi], bv[ni], acc[mi][ni], 0, 0, 0);
        }
    };

    LOAD(0);
    WRITE(0);
    __syncthreads();
    int cur = 0;
    for (int k0 = 64; k0 < K; k0 += 64) {
        LOAD(k0);            // next tile -> regs (latency hides under MFMA)
        COMPUTE(cur);        // MFMA on current buffer
        WRITE(cur ^ 1);      // convert+write next buffer
        __syncthreads();     // one barrier per K-step
        cur ^= 1;
    }
    COMPUTE(cur);

    // epilogue: D[m=(lane>>4)*4+r][n=lane&15] per 16x16 fragment
    #pragma unroll
    for (int mi = 0; mi < 4; ++mi) {
        #pragma unroll
        for (int r = 0; r < 4; ++r) {
            const int srow2 = rowbase + wr + mi * 16 + ((lane >> 4) << 2) + r;
            if (act <= 1) {
                #pragma unroll
                for (int ni = 0; ni < 4; ++ni) {
                    float v = acc[mi][ni][r];
                    if (act == 1) v = v / (1.f + expf(-v));
                    out[(size_t)srow2 * N + colbase + wc + ni * 16 + lm] = v;
                }
            } else {
                const int b2  = srow2 >> 10;
                const int ts2 = srow2 & (TT - 1);
                const int t2  = dir ? (TT - 1 - ts2) : ts2;
                float* op = out + (size_t)(b2 * TT + t2) * CC + colbase + wc + lm;
                if (act == 4) {
                    #pragma unroll
                    for (int ni = 0; ni < 4; ++ni)
                        op[ni * 16] = acc[mi][ni][r];
                } else {
                    const float mv = mask_val(mask, b2 * TT + t2);
                    #pragma unroll
                    for (int ni = 0; ni < 4; ++ni)
                        op[ni * 16] = (op[ni * 16] + acc[mi][ni][r]) * mv;
                }
            }
        }
    }
}

// ---------------- fp32 lora1 (x-mix @ dw1, tanh), 16-row tiles ----------------
__global__ __launch_bounds__(256)
void lora1_kernel(const float* __restrict__ x, const float* __restrict__ mu,
                  const float* __restrict__ dw1, float* __restrict__ out,
                  const int dir)
{
    __shared__ float As[16][68];
    __shared__ float Bs[64][68];
    const int tid = threadIdx.x;
    const int rowbase = blockIdx.x << 4;

    const int arow = tid >> 4;
    const int akq  = (tid & 15) << 2;
    const int s  = rowbase + arow;
    const int bb = s >> 10, ts = s & (TT - 1);
    const int t  = dir ? (TT - 1 - ts) : ts;
    const int tp = dir ? (t + 1) : (t - 1);

    const int c0 = tid & 63;
    const int r4 = tid >> 6;

    float acc[4] = {0.f, 0.f, 0.f, 0.f};

    for (int k0 = 0; k0 < CC; k0 += 64) {
        {
            const int c = k0 + akq;
            const float4 xa = *reinterpret_cast<const float4*>(
                x + (size_t)(bb * TT + t) * CC + c);
            float4 xp = make_float4(0.f, 0.f, 0.f, 0.f);
            if (ts > 0)
                xp = *reinterpret_cast<const float4*>(
                    x + (size_t)(bb * TT + tp) * CC + c);
            const float4 m4 = *reinterpret_cast<const float4*>(mu + c);
            float4 va;
            va.x = fmaf(xp.x - xa.x, m4.x, xa.x);
            va.y = fmaf(xp.y - xa.y, m4.y, xa.y);
            va.z = fmaf(xp.z - xa.z, m4.z, xa.z);
            va.w = fmaf(xp.w - xa.w, m4.w, xa.w);
            *reinterpret_cast<float4*>(&As[arow][akq]) = va;
        }
        #pragma unroll
        for (int it = 0; it < 4; ++it) {
            const int c2 = tid + (it << 8);
            const int brow = c2 >> 4, bcol = (c2 & 15) << 2;
            *reinterpret_cast<float4*>(&Bs[brow][bcol]) =
                *reinterpret_cast<const float4*>(
                    dw1 + (size_t)(k0 + brow) * LR + bcol);
        }
        __syncthreads();
        #pragma unroll
        for (int k4 = 0; k4 < 16; ++k4) {
            float bv[4];
            #pragma unroll
            for (int q = 0; q < 4; ++q) bv[q] = Bs[(k4 << 2) + q][c0];
            #pragma unroll
            for (int i = 0; i < 4; ++i) {
                const float4 a4 = *reinterpret_cast<const float4*>(
                    &As[r4 + (i << 2)][k4 << 2]);
                acc[i] = fmaf(a4.x, bv[0], acc[i]);
                acc[i] = fmaf(a4.y, bv[1], acc[i]);
                acc[i] = fmaf(a4.z, bv[2], acc[i]);
                acc[i] = fmaf(a4.w, bv[3], acc[i]);
            }
        }
        __syncthreads();
    }
    #pragma unroll
    for (int i = 0; i < 4; ++i)
        out[(size_t)(rowbase + r4 + (i << 2)) * LR + c0] = tanhf(acc[i]);
}

// ---------------- fp32 GEMM (lora2: decay exp(-exp)) ----------------
__global__ __launch_bounds__(256)
void gemm_kernel(const float* __restrict__ Ap, const float* __restrict__ W,
                 const float* __restrict__ bias, float* __restrict__ out,
                 const int K, const int N)
{
    __shared__ float As[16][68];
    __shared__ float Bs[16][68];
    const int tid = threadIdx.x;
    const int rowbase = blockIdx.x << 6;
    const int colbase = blockIdx.y << 6;
    const int ty = tid >> 4, tx = tid & 15;
    const int am = tid >> 2;
    const int aq = tid & 3;
    const int s  = rowbase + am;
    const int bk = tid >> 4;
    const int bn = (tid & 15) << 2;

    float acc[4][4];
    #pragma unroll
    for (int i = 0; i < 4; ++i)
        #pragma unroll
        for (int j = 0; j < 4; ++j) acc[i][j] = 0.f;

    for (int k0 = 0; k0 < K; k0 += 16) {
        const float4 va = *reinterpret_cast<const float4*>(
            Ap + (size_t)s * K + k0 + (aq << 2));
        const float4 vb = *reinterpret_cast<const float4*>(
            W + (size_t)(k0 + bk) * N + colbase + bn);
        As[(aq << 2) + 0][am] = va.x;
        As[(aq << 2) + 1][am] = va.y;
        As[(aq << 2) + 2][am] = va.z;
        As[(aq << 2) + 3][am] = va.w;
        *reinterpret_cast<float4*>(&Bs[bk][bn]) = vb;
        __syncthreads();
        #pragma unroll
        for (int kk = 0; kk < 16; ++kk) {
            const float4 a  = *reinterpret_cast<const float4*>(&As[kk][ty << 2]);
            const float4 bv = *reinterpret_cast<const float4*>(&Bs[kk][tx << 2]);
            const float av[4]  = {a.x, a.y, a.z, a.w};
            const float bvv[4] = {bv.x, bv.y, bv.z, bv.w};
            #pragma unroll
            for (int i = 0; i < 4; ++i)
                #pragma unroll
                for (int j = 0; j < 4; ++j)
                    acc[i][j] = fmaf(av[i], bvv[j], acc[i][j]);
        }
        __syncthreads();
    }

    #pragma unroll
    for (int i = 0; i < 4; ++i) {
        const int srow = rowbase + (ty << 2) + i;
        const int ncol = colbase + (tx << 2);
        float v[4];
        #pragma unroll
        for (int j = 0; j < 4; ++j)
            v[j] = expf(-expf(acc[i][j] + bias[ncol + j]));
        *reinterpret_cast<float4*>(out + (size_t)srow * N + ncol) =
            make_float4(v[0], v[1], v[2], v[3]);
    }
}

// ---------------- chunked scan (A/B/C) ----------------
template<int L>
__global__ __launch_bounds__(64)
void scanA_kernel(const float* __restrict__ kbuf, const float* __restrict__ vbuf,
                  const float* __restrict__ wbuf,
                  float* __restrict__ SL, float* __restrict__ Pbuf)
{
    const int c = blockIdx.x, h = blockIdx.y, b = blockIdx.z;
    const int e = threadIdx.x;
    const size_t base = (size_t)(b * TT + c * L) * CC + h * DD;

    float S[DD];
    #pragma unroll
    for (int d = 0; d < DD; ++d) S[d] = 0.f;
    float P = 1.f;

    float ve = vbuf[base + e];
    float we = wbuf[base + e];
    for (int t = 0; t < L; ++t) {
        float ve2 = 0.f, we2 = 0.f;
        if (t + 1 < L) {
            ve2 = vbuf[base + (size_t)(t + 1) * CC + e];
            we2 = wbuf[base + (size_t)(t + 1) * CC + e];
        }
        const float* __restrict__ kk = kbuf + base + (size_t)t * CC;  // uniform
        const float* __restrict__ ww = wbuf + base + (size_t)t * CC;  // uniform
        P *= we;
        #pragma unroll
        for (int d = 0; d < DD; ++d) {
            const float kd = kk[d];
            const float wd = ww[d];
            S[d] = fmaf(wd, S[d], kd * ve);
        }
        ve = ve2; we = we2;
    }

    float* slot = SL + (size_t)((c * BBB + b) * HH + h) * DD * DD;
    #pragma unroll
    for (int d = 0; d < DD; ++d) slot[d * DD + e] = S[d];
    Pbuf[(size_t)((c * BBB + b) * HH + h) * DD + e] = P;
}

__global__ __launch_bounds__(64)
void scanB_kernel(float* __restrict__ SL, const float* __restrict__ Pbuf,
                  const int nch)
{
    const int h = blockIdx.x, b = blockIdx.y, dg = blockIdx.z;
    const int e = threadIdx.x;
    const size_t doff = (size_t)dg * 16 * DD;

    float S[16];
    #pragma unroll
    for (int i = 0; i < 16; ++i) S[i] = 0.f;

    float sl[16], pp[16];
    {
        const float* s0 = SL + (size_t)(b * HH + h) * DD * DD + doff;
        const float* p0 = Pbuf + (size_t)(b * HH + h) * DD + dg * 16;
        #pragma unroll
        for (int i = 0; i < 16; ++i) { sl[i] = s0[i * DD + e]; pp[i] = p0[i]; }
    }
    for (int c = 0; c < nch; ++c) {
        float sl2[16], pp2[16];
        if (c + 1 < nch) {
            const float* s1 = SL + (size_t)(((c + 1) * BBB + b) * HH + h) * DD * DD + doff;
            const float* p1 = Pbuf + (size_t)(((c + 1) * BBB + b) * HH + h) * DD + dg * 16;
            #pragma unroll
            for (int i = 0; i < 16; ++i) { sl2[i] = s1[i * DD + e]; pp2[i] = p1[i]; }
        }
        float* sc = SL + (size_t)((c * BBB + b) * HH + h) * DD * DD + doff;
        #pragma unroll
        for (int i = 0; i < 16; ++i) {
            S[i] = fmaf(pp[i], S[i], sl[i]);
            sc[i * DD + e] = S[i];
        }
        #pragma unroll
        for (int i = 0; i < 16; ++i) { sl[i] = sl2[i]; pp[i] = pp2[i]; }
    }
}

template<int L>
__global__ __launch_bounds__(64)
void scanC_kernel(const float* __restrict__ rbuf, const float* __restrict__ kbuf,
                  const float* __restrict__ vbuf, const float* __restrict__ wbuf,
                  const float* __restrict__ gbuf, const float* __restrict__ SL,
                  const float* __restrict__ u, const float* __restrict__ lnw,
                  const float* __restrict__ lnb, u16* __restrict__ zb,
                  const int dir)
{
    __shared__ float ys[L * 65];
    __shared__ float pcs[L * 65];
    __shared__ float vs[L * 65];
    __shared__ float redm[L], redi[L];

    const int c = blockIdx.x, h = blockIdx.y, b = blockIdx.z;
    const int e = threadIdx.x;
    const size_t base = (size_t)(b * TT + c * L) * CC + h * DD;

    const float ue = u[(size_t)(dir * HH + h) * DD + e];
    const float gw = lnw[dir * CC + h * DD + e];
    const float gb = lnb[dir * CC + h * DD + e];

    float S[DD];
    if (c == 0) {
        #pragma unroll
        for (int d = 0; d < DD; ++d) S[d] = 0.f;
    } else {
        const float* slot = SL + (size_t)(((c - 1) * BBB + b) * HH + h) * DD * DD;
        #pragma unroll
        for (int d = 0; d < DD; ++d) S[d] = slot[d * DD + e];
    }

    float ve = vbuf[base + e];
    float re = rbuf[base + e];
    float ke = kbuf[base + e];
    for (int t = 0; t < L; ++t) {
        float ve2 = 0.f, re2 = 0.f, ke2 = 0.f;
        if (t + 1 < L) {
            ve2 = vbuf[base + (size_t)(t + 1) * CC + e];
            re2 = rbuf[base + (size_t)(t + 1) * CC + e];
            ke2 = kbuf[base + (size_t)(t + 1) * CC + e];
        }
        const float* __restrict__ rr = rbuf + base + (size_t)t * CC;  // uniform
        const float* __restrict__ kk = kbuf + base + (size_t)t * CC;  // uniform
        const float* __restrict__ ww = wbuf + base + (size_t)t * CC;  // uniform

        float y = 0.f;
        #pragma unroll
        for (int d = 0; d < DD; ++d) {
            const float rd = rr[d];
            const float kd = kk[d];
            const float wd = ww[d];
            y = fmaf(rd, S[d], y);
            S[d] = fmaf(wd, S[d], kd * ve);
        }
        ys[t * 65 + e]  = y;
        pcs[t * 65 + e] = re * ue * ke;
        vs[t * 65 + e]  = ve;
        ve = ve2; re = re2; ke = ke2;
    }
    __syncthreads();

    constexpr int HPT = (L >= 64) ? 1 : (64 / L);
    constexpr int SEG = 64 / HPT;
    {
        const int t1 = e / HPT;
        const int h1 = e % HPT;
        const int off = t1 * 65 + h1 * SEG;
        float cp = 0.f;
        #pragma unroll
        for (int jq = 0; jq < SEG; ++jq) cp += pcs[off + jq];
        if (HPT == 2) cp += __shfl_xor(cp, 1);
        float sm = 0.f, sq = 0.f;
        #pragma unroll
        for (int jq = 0; jq < SEG; ++jq) {
            const float yf = fmaf(cp, vs[off + jq], ys[off + jq]);
            ys[off + jq] = yf;
            sm += yf;
            sq = fmaf(yf, yf, sq);
        }
        if (HPT == 2) { sm += __shfl_xor(sm, 1); sq += __shfl_xor(sq, 1); }
        if (h1 == 0) {
            const float mean = sm * (1.f / 64.f);
            const float var  = fmaf(-mean, mean, sq * (1.f / 64.f));
            redm[t1] = mean;
            redi[t1] = rsqrtf(var + 1e-5f);
        }
    }
    __syncthreads();

    for (int t = 0; t < L; ++t) {
        const float yf = ys[t * 65 + e];
        const float yn = (yf - redm[t]) * redi[t] * gw + gb;
        zb[base + (size_t)t * CC + e] =
            f2h(yn * gbuf[base + (size_t)t * CC + e]);
    }
}

extern "C" void kernel_launch(void* const* d_in, const int* in_sizes, int n_in,
                              void* d_out, int out_size, void* d_ws, size_t ws_size,
                              hipStream_t stream)
{
    const float* x     = (const float*)d_in[0];
    const void*  mask  = d_in[1];
    const float* mu    = (const float*)d_in[2];
    const float* wbias = (const float*)d_in[3];
    const float* dw1   = (const float*)d_in[4];
    const float* dw2   = (const float*)d_in[5];
    const float* u     = (const float*)d_in[6];
    const float* Wr    = (const float*)d_in[7];
    const float* Wk    = (const float*)d_in[8];
    const float* Wv    = (const float*)d_in[9];
    const float* Wg    = (const float*)d_in[10];
    const float* Wo    = (const float*)d_in[11];
    const float* lnw   = (const float*)d_in[12];
    const float* lnb   = (const float*)d_in[13];
    float* out = (float*)d_out;

    float* ws = (float*)d_ws;
    const size_t NBT = (size_t)BT * CC;
    const size_t MUN = 2 * 5 * CC;

    auto need_bytes = [&](int nch) -> size_t {
        const size_t fl = 5 * NBT + (size_t)BT * LR
                        + (size_t)nch * BBB * HH * DD * DD
                        + (size_t)nch * BBB * HH * DD;
        const size_t hw = 2 * NBT + (size_t)10 * WSQ + MUN;
        return fl * 4 + hw * 2;
    };
    const int nch = (ws_size >= need_bytes(32)) ? 32 : 16;

    float* rbuf  = ws;
    float* kbuf  = rbuf  + NBT;
    float* vbuf  = kbuf  + NBT;
    float* wwbuf = vbuf  + NBT;
    float* gbuf  = wwbuf + NBT;
    float* lora  = gbuf  + NBT;
    float* SL    = lora  + (size_t)BT * LR;
    float* Pbuf  = SL    + (size_t)nch * BBB * HH * DD * DD;
    u16*   zb    = (u16*)(Pbuf + (size_t)nch * BBB * HH * DD);
    u16*   xbb   = zb + NBT;
    u16*   wtb   = xbb + NBT;
    u16*   muh   = wtb + (size_t)10 * WSQ;

    TP10 tj;
    const float* Wlist[5] = {Wr, Wk, Wv, Wg, Wo};
    for (int dir = 0; dir < 2; ++dir)
        for (int i = 0; i < 5; ++i)
            tj.src[dir * 5 + i] = Wlist[i] + (size_t)dir * WSQ;
    transpose_conv<<<dim3(24, 24, 10), 256, 0, stream>>>(tj, wtb);
    convert_x<<<dim3(NBT / (8 * 256)), 256, 0, stream>>>(x, xbb);
    convert_mu<<<dim3((MUN + 255) / 256), 256, 0, stream>>>(mu, muh, (int)MUN);

    const dim3 gridBig(BT / 128, CC / 128, 4);
    const dim3 gridOut(BT / 128, CC / 128, 1);

    for (int dir = 0; dir < 2; ++dir) {
        const float* muD = mu + (size_t)dir * 5 * CC;
        const u16* muhD = muh + (size_t)dir * 5 * CC;
        const u16* wt = wtb + (size_t)dir * 5 * WSQ;

        GB pb;
        pb.Wt[0] = wt + 0 * WSQ; pb.out[0] = rbuf; pb.mu[0] = muhD + 0 * CC; pb.act[0] = 0;
        pb.Wt[1] = wt + 1 * WSQ; pb.out[1] = kbuf; pb.mu[1] = muhD + 1 * CC; pb.act[1] = 0;
        pb.Wt[2] = wt + 2 * WSQ; pb.out[2] = vbuf; pb.mu[2] = muhD + 2 * CC; pb.act[2] = 0;
        pb.Wt[3] = wt + 3 * WSQ; pb.out[3] = gbuf; pb.mu[3] = muhD + 4 * CC; pb.act[3] = 1;
        gemm_mfma_big<<<gridBig, 256, 0, stream>>>(pb, nullptr, xbb, nullptr,
                                                   CC, CC, dir, 1);

        lora1_kernel<<<dim3(BT / 16), 256, 0, stream>>>(x, muD + 3 * CC,
                                                        dw1 + (size_t)dir * CC * LR,
                                                        lora, dir);
        gemm_kernel<<<dim3(BT / 64, CC / 64), 256, 0, stream>>>(
            lora, dw2 + (size_t)dir * LR * CC, wbias + (size_t)dir * CC,
            wwbuf, LR, CC);

        if (nch == 32) {
            scanA_kernel<32><<<dim3(32, HH, BBB), dim3(64), 0, stream>>>(
                kbuf, vbuf, wwbuf, SL, Pbuf);
            scanB_kernel<<<dim3(HH, BBB, 4), dim3(64), 0, stream>>>(SL, Pbuf, 32);
            scanC_kernel<32><<<dim3(32, HH, BBB), dim3(64), 0, stream>>>(
                rbuf, kbuf, vbuf, wwbuf, gbuf, SL, u, lnw, lnb, zb, dir);
        } else {
            scanA_kernel<64><<<dim3(16, HH, BBB), dim3(64), 0, stream>>>(
                kbuf, vbuf, wwbuf, SL, Pbuf);
            scanB_kernel<<<dim3(HH, BBB, 4), dim3(64), 0, stream>>>(SL, Pbuf, 16);
            scanC_kernel<64><<<dim3(16, HH, BBB), dim3(64), 0, stream>>>(
                rbuf, kbuf, vbuf, wwbuf, gbuf, SL, u, lnw, lnb, zb, dir);
        }

        GB po;
        po.Wt[0] = wt + 4 * WSQ; po.out[0] = out; po.mu[0] = nullptr;
        po.act[0] = (dir == 0) ? 4 : 5;
        po.Wt[1] = po.Wt[0]; po.out[1] = out; po.mu[1] = nullptr; po.act[1] = po.act[0];
        po.Wt[2] = po.Wt[0]; po.out[2] = out; po.mu[2] = nullptr; po.act[2] = po.act[0];
        po.Wt[3] = po.Wt[0]; po.out[3] = out; po.mu[3] = nullptr; po.act[3] = po.act[0];
        gemm_mfma_big<<<gridOut, 256, 0, stream>>>(po, zb, nullptr, mask,
                                                   CC, CC, dir, 0);
    }
}

// Round 9
// 695.296 us; speedup vs baseline: 1.1011x; 1.1011x over previous
//
#include <hip/hip_runtime.h>
#include <cstdint>
#include <cstddef>

// BiRWKV (RWKV-6 bidirectional time-mix), B=4 T=1024 C=768 H=12 D=64 LORA=64.
// Round 9: round-7 GEMM skeleton (512 thr, 8 waves, single 36KB LDS buffer)
// + register prefetch across COMPUTE (stage regs: 2 groups, 32 VGPR — no
// spill, unlike round 8's 4-group/64-VGPR version that spilled to scratch)
// + packed-fp16 token-shift mix (validated in round 8: same absmax).

#define HH   12
#define DD   64
#define CC   768
#define TT   1024
#define BBB  4
#define LR   64
#define BT   (BBB*TT)
#define WSQ  (CC*CC)

typedef unsigned short u16;
typedef _Float16 f16x8 __attribute__((ext_vector_type(8)));  // 8 f16 (4 VGPRs)
typedef float f32x4 __attribute__((ext_vector_type(4)));     // MFMA accumulator

__device__ __forceinline__ u16 f2h(float f) {
    const _Float16 h = (_Float16)f;
    return __builtin_bit_cast(u16, h);
}
__device__ __forceinline__ float h2f(u16 h) {
    return (float)__builtin_bit_cast(_Float16, h);
}

// pad_mask dtype detect (bool bytes vs int32 vs float32).
__device__ __forceinline__ float mask_val(const void* mp, int idx) {
    const unsigned char* b = (const unsigned char*)mp;
    const int i0 = ((const int*)mp)[0];
    if (i0 == 0x3f800000) {
        return ((const float*)mp)[idx] != 0.f ? 1.f : 0.f;
    }
    if ((b[1] | b[2] | b[3]) == 0) {
        return ((const int*)mp)[idx] != 0 ? 1.f : 0.f;
    }
    return b[idx] ? 1.f : 0.f;
}

// ---------------- prepass: weight transpose-convert, x/mu convert ----------------
struct TP10 { const float* src[10]; };

__global__ __launch_bounds__(256)
void transpose_conv(TP10 tj, u16* __restrict__ dst)
{
    __shared__ float sh[32][33];
    const int j = blockIdx.z;
    const float* __restrict__ src = tj.src[j];
    u16* __restrict__ d = dst + (size_t)j * WSQ;
    const int n0 = blockIdx.x << 5, k0 = blockIdx.y << 5;
    const int tx = threadIdx.x & 31, ty = threadIdx.x >> 5;
    #pragma unroll
    for (int i = 0; i < 4; ++i)
        sh[ty + (i << 3)][tx] = src[(size_t)(k0 + ty + (i << 3)) * CC + n0 + tx];
    __syncthreads();
    #pragma unroll
    for (int i = 0; i < 4; ++i)
        d[(size_t)(n0 + ty + (i << 3)) * CC + k0 + tx] =
            f2h(sh[tx][ty + (i << 3)]);
}

__global__ __launch_bounds__(256)
void convert_x(const float* __restrict__ x, u16* __restrict__ xb)
{
    const size_t off = ((size_t)blockIdx.x * 256 + threadIdx.x) * 8;
    const float4 a = *reinterpret_cast<const float4*>(x + off);
    const float4 b = *reinterpret_cast<const float4*>(x + off + 4);
    uint4 w;
    w.x = (unsigned)f2h(a.x) | ((unsigned)f2h(a.y) << 16);
    w.y = (unsigned)f2h(a.z) | ((unsigned)f2h(a.w) << 16);
    w.z = (unsigned)f2h(b.x) | ((unsigned)f2h(b.y) << 16);
    w.w = (unsigned)f2h(b.z) | ((unsigned)f2h(b.w) << 16);
    *reinterpret_cast<uint4*>(xb + off) = w;
}

__global__ __launch_bounds__(256)
void convert_mu(const float* __restrict__ mu, u16* __restrict__ muh, int n)
{
    const int i = blockIdx.x * 256 + threadIdx.x;
    if (i < n) muh[i] = f2h(mu[i]);
}

// ---------------- fp16 MFMA GEMM: 128x128 tile, 8 waves (64x32 each) -----------
// single LDS buffer, register prefetch across COMPUTE, packed-fp16 mix.
struct GB { const u16* Wt[4]; float* out[4]; const u16* mu[4]; int act[4]; };

__global__ __launch_bounds__(512)
void gemm_mfma_big(GB p, const u16* __restrict__ Ab, const u16* __restrict__ xb,
                   const void* __restrict__ mask,
                   const int K, const int N, const int dir, const int mixA)
{
    const int j = blockIdx.z;
    const u16* __restrict__ Wt = p.Wt[j];
    float* __restrict__ out = p.out[j];
    const u16* __restrict__ muh = p.mu[j];
    const int act = p.act[j];

    __shared__ __align__(16) u16 Als[128][72];
    __shared__ __align__(16) u16 Bls[128][72];
    const int tid = threadIdx.x;
    const int rowbase = blockIdx.x << 7;
    const int colbase = blockIdx.y << 7;
    const int lane = tid & 63;
    const int wid = tid >> 6;           // 0..7
    const int wr = (wid >> 2) << 6;     // 0 / 64
    const int wc = (wid & 3) << 5;      // 0,32,64,96
    const int lm = lane & 15;
    const int lk = (lane >> 4) << 3;    // 0,8,16,24

    // staging geometry: 2 groups of (row, kq) per thread
    int srow[2], skq[2], sb[2], st[2], stp[2], sts[2];
    #pragma unroll
    for (int it = 0; it < 2; ++it) {
        const int g = tid + (it << 9);
        srow[it] = g >> 3;
        skq[it]  = (g & 7) << 3;
        const int s = rowbase + srow[it];
        sb[it] = s >> 10;
        const int ts = s & (TT - 1);
        sts[it] = ts;
        const int t = dir ? (TT - 1 - ts) : ts;
        st[it]  = t;
        stp[it] = dir ? (t + 1) : (t - 1);
    }

    uint4 aR[2], pR[2], mR[2], bR[2];

    auto LOAD = [&](int k0) {
        #pragma unroll
        for (int it = 0; it < 2; ++it) {
            bR[it] = *reinterpret_cast<const uint4*>(
                Wt + (size_t)(colbase + srow[it]) * K + k0 + skq[it]);
            if (mixA) {
                aR[it] = *reinterpret_cast<const uint4*>(
                    xb + (size_t)(sb[it] * TT + st[it]) * CC + k0 + skq[it]);
                pR[it] = make_uint4(0u, 0u, 0u, 0u);
                if (sts[it] > 0)
                    pR[it] = *reinterpret_cast<const uint4*>(
                        xb + (size_t)(sb[it] * TT + stp[it]) * CC + k0 + skq[it]);
                mR[it] = *reinterpret_cast<const uint4*>(muh + k0 + skq[it]);
            } else {
                aR[it] = *reinterpret_cast<const uint4*>(
                    Ab + (size_t)(rowbase + srow[it]) * K + k0 + skq[it]);
            }
        }
    };
    auto WRITE = [&]() {
        #pragma unroll
        for (int it = 0; it < 2; ++it) {
            *reinterpret_cast<uint4*>(&Bls[srow[it]][skq[it]]) = bR[it];
            if (mixA) {
                const f16x8 xa = __builtin_bit_cast(f16x8, aR[it]);
                const f16x8 xp = __builtin_bit_cast(f16x8, pR[it]);
                const f16x8 mm = __builtin_bit_cast(f16x8, mR[it]);
                const f16x8 res = (xp - xa) * mm + xa;   // v_pk_* fp16
                *reinterpret_cast<uint4*>(&Als[srow[it]][skq[it]]) =
                    __builtin_bit_cast(uint4, res);
            } else {
                *reinterpret_cast<uint4*>(&Als[srow[it]][skq[it]]) = aR[it];
            }
        }
    };

    f32x4 acc[4][2] = {};
    auto COMPUTE = [&]() {
        #pragma unroll
        for (int ks = 0; ks < 2; ++ks) {
            const int ko = (ks << 5) + lk;
            f16x8 av[4], bv[2];
            #pragma unroll
            for (int mi = 0; mi < 4; ++mi)
                av[mi] = *reinterpret_cast<const f16x8*>(&Als[wr + mi * 16 + lm][ko]);
            #pragma unroll
            for (int ni = 0; ni < 2; ++ni)
                bv[ni] = *reinterpret_cast<const f16x8*>(&Bls[wc + ni * 16 + lm][ko]);
            #pragma unroll
            for (int mi = 0; mi < 4; ++mi)
                #pragma unroll
                for (int ni = 0; ni < 2; ++ni)
                    acc[mi][ni] = __builtin_amdgcn_mfma_f32_16x16x32_f16(
                        av[mi], bv[ni], acc[mi][ni], 0, 0, 0);
        }
    };

    LOAD(0);
    for (int k0 = 0; k0 < K; k0 += 64) {
        WRITE();                      // write tile k0 (regs) to LDS
        __syncthreads();
        if (k0 + 64 < K) LOAD(k0 + 64);   // issue next loads; wait is at next WRITE
        COMPUTE();                    // MFMA on tile k0
        __syncthreads();
    }

    // epilogue: D[m=(lane>>4)*4+r][n=lane&15] per 16x16 fragment
    #pragma unroll
    for (int mi = 0; mi < 4; ++mi) {
        #pragma unroll
        for (int r = 0; r < 4; ++r) {
            const int srow2 = rowbase + wr + mi * 16 + ((lane >> 4) << 2) + r;
            float v0 = acc[mi][0][r];
            float v1 = acc[mi][1][r];
            if (act == 1) {
                v0 = v0 / (1.f + expf(-v0));
                v1 = v1 / (1.f + expf(-v1));
            }
            const int col = colbase + wc + lm;
            if (act <= 1) {
                out[(size_t)srow2 * N + col]      = v0;
                out[(size_t)srow2 * N + col + 16] = v1;
            } else {
                const int b2  = srow2 >> 10;
                const int ts2 = srow2 & (TT - 1);
                const int t2  = dir ? (TT - 1 - ts2) : ts2;
                float* op = out + (size_t)(b2 * TT + t2) * CC + col;
                if (act == 4) {
                    op[0]  = v0;
                    op[16] = v1;
                } else {
                    const float mv = mask_val(mask, b2 * TT + t2);
                    op[0]  = (op[0]  + v0) * mv;
                    op[16] = (op[16] + v1) * mv;
                }
            }
        }
    }
}

// ---------------- fp32 lora1 (x-mix @ dw1, tanh), 16-row tiles ----------------
__global__ __launch_bounds__(256)
void lora1_kernel(const float* __restrict__ x, const float* __restrict__ mu,
                  const float* __restrict__ dw1, float* __restrict__ out,
                  const int dir)
{
    __shared__ float As[16][68];
    __shared__ float Bs[64][68];
    const int tid = threadIdx.x;
    const int rowbase = blockIdx.x << 4;

    const int arow = tid >> 4;
    const int akq  = (tid & 15) << 2;
    const int s  = rowbase + arow;
    const int bb = s >> 10, ts = s & (TT - 1);
    const int t  = dir ? (TT - 1 - ts) : ts;
    const int tp = dir ? (t + 1) : (t - 1);

    const int c0 = tid & 63;
    const int r4 = tid >> 6;

    float acc[4] = {0.f, 0.f, 0.f, 0.f};

    for (int k0 = 0; k0 < CC; k0 += 64) {
        {
            const int c = k0 + akq;
            const float4 xa = *reinterpret_cast<const float4*>(
                x + (size_t)(bb * TT + t) * CC + c);
            float4 xp = make_float4(0.f, 0.f, 0.f, 0.f);
            if (ts > 0)
                xp = *reinterpret_cast<const float4*>(
                    x + (size_t)(bb * TT + tp) * CC + c);
            const float4 m4 = *reinterpret_cast<const float4*>(mu + c);
            float4 va;
            va.x = fmaf(xp.x - xa.x, m4.x, xa.x);
            va.y = fmaf(xp.y - xa.y, m4.y, xa.y);
            va.z = fmaf(xp.z - xa.z, m4.z, xa.z);
            va.w = fmaf(xp.w - xa.w, m4.w, xa.w);
            *reinterpret_cast<float4*>(&As[arow][akq]) = va;
        }
        #pragma unroll
        for (int it = 0; it < 4; ++it) {
            const int c2 = tid + (it << 8);
            const int brow = c2 >> 4, bcol = (c2 & 15) << 2;
            *reinterpret_cast<float4*>(&Bs[brow][bcol]) =
                *reinterpret_cast<const float4*>(
                    dw1 + (size_t)(k0 + brow) * LR + bcol);
        }
        __syncthreads();
        #pragma unroll
        for (int k4 = 0; k4 < 16; ++k4) {
            float bv[4];
            #pragma unroll
            for (int q = 0; q < 4; ++q) bv[q] = Bs[(k4 << 2) + q][c0];
            #pragma unroll
            for (int i = 0; i < 4; ++i) {
                const float4 a4 = *reinterpret_cast<const float4*>(
                    &As[r4 + (i << 2)][k4 << 2]);
                acc[i] = fmaf(a4.x, bv[0], acc[i]);
                acc[i] = fmaf(a4.y, bv[1], acc[i]);
                acc[i] = fmaf(a4.z, bv[2], acc[i]);
                acc[i] = fmaf(a4.w, bv[3], acc[i]);
            }
        }
        __syncthreads();
    }
    #pragma unroll
    for (int i = 0; i < 4; ++i)
        out[(size_t)(rowbase + r4 + (i << 2)) * LR + c0] = tanhf(acc[i]);
}

// ---------------- fp32 GEMM (lora2: decay exp(-exp)) ----------------
__global__ __launch_bounds__(256)
void gemm_kernel(const float* __restrict__ Ap, const float* __restrict__ W,
                 const float* __restrict__ bias, float* __restrict__ out,
                 const int K, const int N)
{
    __shared__ float As[16][68];
    __shared__ float Bs[16][68];
    const int tid = threadIdx.x;
    const int rowbase = blockIdx.x << 6;
    const int colbase = blockIdx.y << 6;
    const int ty = tid >> 4, tx = tid & 15;
    const int am = tid >> 2;
    const int aq = tid & 3;
    const int s  = rowbase + am;
    const int bk = tid >> 4;
    const int bn = (tid & 15) << 2;

    float acc[4][4];
    #pragma unroll
    for (int i = 0; i < 4; ++i)
        #pragma unroll
        for (int j = 0; j < 4; ++j) acc[i][j] = 0.f;

    for (int k0 = 0; k0 < K; k0 += 16) {
        const float4 va = *reinterpret_cast<const float4*>(
            Ap + (size_t)s * K + k0 + (aq << 2));
        const float4 vb = *reinterpret_cast<const float4*>(
            W + (size_t)(k0 + bk) * N + colbase + bn);
        As[(aq << 2) + 0][am] = va.x;
        As[(aq << 2) + 1][am] = va.y;
        As[(aq << 2) + 2][am] = va.z;
        As[(aq << 2) + 3][am] = va.w;
        *reinterpret_cast<float4*>(&Bs[bk][bn]) = vb;
        __syncthreads();
        #pragma unroll
        for (int kk = 0; kk < 16; ++kk) {
            const float4 a  = *reinterpret_cast<const float4*>(&As[kk][ty << 2]);
            const float4 bv = *reinterpret_cast<const float4*>(&Bs[kk][tx << 2]);
            const float av[4]  = {a.x, a.y, a.z, a.w};
            const float bvv[4] = {bv.x, bv.y, bv.z, bv.w};
            #pragma unroll
            for (int i = 0; i < 4; ++i)
                #pragma unroll
                for (int j = 0; j < 4; ++j)
                    acc[i][j] = fmaf(av[i], bvv[j], acc[i][j]);
        }
        __syncthreads();
    }

    #pragma unroll
    for (int i = 0; i < 4; ++i) {
        const int srow = rowbase + (ty << 2) + i;
        const int ncol = colbase + (tx << 2);
        float v[4];
        #pragma unroll
        for (int j = 0; j < 4; ++j)
            v[j] = expf(-expf(acc[i][j] + bias[ncol + j]));
        *reinterpret_cast<float4*>(out + (size_t)srow * N + ncol) =
            make_float4(v[0], v[1], v[2], v[3]);
    }
}

// ---------------- chunked scan (A/B/C) ----------------
template<int L>
__global__ __launch_bounds__(64)
void scanA_kernel(const float* __restrict__ kbuf, const float* __restrict__ vbuf,
                  const float* __restrict__ wbuf,
                  float* __restrict__ SL, float* __restrict__ Pbuf)
{
    const int c = blockIdx.x, h = blockIdx.y, b = blockIdx.z;
    const int e = threadIdx.x;
    const size_t base = (size_t)(b * TT + c * L) * CC + h * DD;

    float S[DD];
    #pragma unroll
    for (int d = 0; d < DD; ++d) S[d] = 0.f;
    float P = 1.f;

    float ve = vbuf[base + e];
    float we = wbuf[base + e];
    for (int t = 0; t < L; ++t) {
        float ve2 = 0.f, we2 = 0.f;
        if (t + 1 < L) {
            ve2 = vbuf[base + (size_t)(t + 1) * CC + e];
            we2 = wbuf[base + (size_t)(t + 1) * CC + e];
        }
        const float* __restrict__ kk = kbuf + base + (size_t)t * CC;  // uniform
        const float* __restrict__ ww = wbuf + base + (size_t)t * CC;  // uniform
        P *= we;
        #pragma unroll
        for (int d = 0; d < DD; ++d) {
            const float kd = kk[d];
            const float wd = ww[d];
            S[d] = fmaf(wd, S[d], kd * ve);
        }
        ve = ve2; we = we2;
    }

    float* slot = SL + (size_t)((c * BBB + b) * HH + h) * DD * DD;
    #pragma unroll
    for (int d = 0; d < DD; ++d) slot[d * DD + e] = S[d];
    Pbuf[(size_t)((c * BBB + b) * HH + h) * DD + e] = P;
}

__global__ __launch_bounds__(64)
void scanB_kernel(float* __restrict__ SL, const float* __restrict__ Pbuf,
                  const int nch)
{
    const int h = blockIdx.x, b = blockIdx.y, dg = blockIdx.z;
    const int e = threadIdx.x;
    const size_t doff = (size_t)dg * 16 * DD;

    float S[16];
    #pragma unroll
    for (int i = 0; i < 16; ++i) S[i] = 0.f;

    float sl[16], pp[16];
    {
        const float* s0 = SL + (size_t)(b * HH + h) * DD * DD + doff;
        const float* p0 = Pbuf + (size_t)(b * HH + h) * DD + dg * 16;
        #pragma unroll
        for (int i = 0; i < 16; ++i) { sl[i] = s0[i * DD + e]; pp[i] = p0[i]; }
    }
    for (int c = 0; c < nch; ++c) {
        float sl2[16], pp2[16];
        if (c + 1 < nch) {
            const float* s1 = SL + (size_t)(((c + 1) * BBB + b) * HH + h) * DD * DD + doff;
            const float* p1 = Pbuf + (size_t)(((c + 1) * BBB + b) * HH + h) * DD + dg * 16;
            #pragma unroll
            for (int i = 0; i < 16; ++i) { sl2[i] = s1[i * DD + e]; pp2[i] = p1[i]; }
        }
        float* sc = SL + (size_t)((c * BBB + b) * HH + h) * DD * DD + doff;
        #pragma unroll
        for (int i = 0; i < 16; ++i) {
            S[i] = fmaf(pp[i], S[i], sl[i]);
            sc[i * DD + e] = S[i];
        }
        #pragma unroll
        for (int i = 0; i < 16; ++i) { sl[i] = sl2[i]; pp[i] = pp2[i]; }
    }
}

template<int L>
__global__ __launch_bounds__(64)
void scanC_kernel(const float* __restrict__ rbuf, const float* __restrict__ kbuf,
                  const float* __restrict__ vbuf, const float* __restrict__ wbuf,
                  const float* __restrict__ gbuf, const float* __restrict__ SL,
                  const float* __restrict__ u, const float* __restrict__ lnw,
                  const float* __restrict__ lnb, u16* __restrict__ zb,
                  const int dir)
{
    __shared__ float ys[L * 65];
    __shared__ float pcs[L * 65];
    __shared__ float vs[L * 65];
    __shared__ float redm[L], redi[L];

    const int c = blockIdx.x, h = blockIdx.y, b = blockIdx.z;
    const int e = threadIdx.x;
    const size_t base = (size_t)(b * TT + c * L) * CC + h * DD;

    const float ue = u[(size_t)(dir * HH + h) * DD + e];
    const float gw = lnw[dir * CC + h * DD + e];
    const float gb = lnb[dir * CC + h * DD + e];

    float S[DD];
    if (c == 0) {
        #pragma unroll
        for (int d = 0; d < DD; ++d) S[d] = 0.f;
    } else {
        const float* slot = SL + (size_t)(((c - 1) * BBB + b) * HH + h) * DD * DD;
        #pragma unroll
        for (int d = 0; d < DD; ++d) S[d] = slot[d * DD + e];
    }

    float ve = vbuf[base + e];
    float re = rbuf[base + e];
    float ke = kbuf[base + e];
    for (int t = 0; t < L; ++t) {
        float ve2 = 0.f, re2 = 0.f, ke2 = 0.f;
        if (t + 1 < L) {
            ve2 = vbuf[base + (size_t)(t + 1) * CC + e];
            re2 = rbuf[base + (size_t)(t + 1) * CC + e];
            ke2 = kbuf[base + (size_t)(t + 1) * CC + e];
        }
        const float* __restrict__ rr = rbuf + base + (size_t)t * CC;  // uniform
        const float* __restrict__ kk = kbuf + base + (size_t)t * CC;  // uniform
        const float* __restrict__ ww = wbuf + base + (size_t)t * CC;  // uniform

        float y = 0.f;
        #pragma unroll
        for (int d = 0; d < DD; ++d) {
            const float rd = rr[d];
            const float kd = kk[d];
            const float wd = ww[d];
            y = fmaf(rd, S[d], y);
            S[d] = fmaf(wd, S[d], kd * ve);
        }
        ys[t * 65 + e]  = y;
        pcs[t * 65 + e] = re * ue * ke;
        vs[t * 65 + e]  = ve;
        ve = ve2; re = re2; ke = ke2;
    }
    __syncthreads();

    constexpr int HPT = (L >= 64) ? 1 : (64 / L);
    constexpr int SEG = 64 / HPT;
    {
        const int t1 = e / HPT;
        const int h1 = e % HPT;
        const int off = t1 * 65 + h1 * SEG;
        float cp = 0.f;
        #pragma unroll
        for (int jq = 0; jq < SEG; ++jq) cp += pcs[off + jq];
        if (HPT == 2) cp += __shfl_xor(cp, 1);
        float sm = 0.f, sq = 0.f;
        #pragma unroll
        for (int jq = 0; jq < SEG; ++jq) {
            const float yf = fmaf(cp, vs[off + jq], ys[off + jq]);
            ys[off + jq] = yf;
            sm += yf;
            sq = fmaf(yf, yf, sq);
        }
        if (HPT == 2) { sm += __shfl_xor(sm, 1); sq += __shfl_xor(sq, 1); }
        if (h1 == 0) {
            const float mean = sm * (1.f / 64.f);
            const float var  = fmaf(-mean, mean, sq * (1.f / 64.f));
            redm[t1] = mean;
            redi[t1] = rsqrtf(var + 1e-5f);
        }
    }
    __syncthreads();

    for (int t = 0; t < L; ++t) {
        const float yf = ys[t * 65 + e];
        const float yn = (yf - redm[t]) * redi[t] * gw + gb;
        zb[base + (size_t)t * CC + e] =
            f2h(yn * gbuf[base + (size_t)t * CC + e]);
    }
}

extern "C" void kernel_launch(void* const* d_in, const int* in_sizes, int n_in,
                              void* d_out, int out_size, void* d_ws, size_t ws_size,
                              hipStream_t stream)
{
    const float* x     = (const float*)d_in[0];
    const void*  mask  = d_in[1];
    const float* mu    = (const float*)d_in[2];
    const float* wbias = (const float*)d_in[3];
    const float* dw1   = (const float*)d_in[4];
    const float* dw2   = (const float*)d_in[5];
    const float* u     = (const float*)d_in[6];
    const float* Wr    = (const float*)d_in[7];
    const float* Wk    = (const float*)d_in[8];
    const float* Wv    = (const float*)d_in[9];
    const float* Wg    = (const float*)d_in[10];
    const float* Wo    = (const float*)d_in[11];
    const float* lnw   = (const float*)d_in[12];
    const float* lnb   = (const float*)d_in[13];
    float* out = (float*)d_out;

    float* ws = (float*)d_ws;
    const size_t NBT = (size_t)BT * CC;
    const size_t MUN = 2 * 5 * CC;

    auto need_bytes = [&](int nch) -> size_t {
        const size_t fl = 5 * NBT + (size_t)BT * LR
                        + (size_t)nch * BBB * HH * DD * DD
                        + (size_t)nch * BBB * HH * DD;
        const size_t hw = 2 * NBT + (size_t)10 * WSQ + MUN;
        return fl * 4 + hw * 2;
    };
    const int nch = (ws_size >= need_bytes(32)) ? 32 : 16;

    float* rbuf  = ws;
    float* kbuf  = rbuf  + NBT;
    float* vbuf  = kbuf  + NBT;
    float* wwbuf = vbuf  + NBT;
    float* gbuf  = wwbuf + NBT;
    float* lora  = gbuf  + NBT;
    float* SL    = lora  + (size_t)BT * LR;
    float* Pbuf  = SL    + (size_t)nch * BBB * HH * DD * DD;
    u16*   zb    = (u16*)(Pbuf + (size_t)nch * BBB * HH * DD);
    u16*   xbb   = zb + NBT;
    u16*   wtb   = xbb + NBT;
    u16*   muh   = wtb + (size_t)10 * WSQ;

    TP10 tj;
    const float* Wlist[5] = {Wr, Wk, Wv, Wg, Wo};
    for (int dir = 0; dir < 2; ++dir)
        for (int i = 0; i < 5; ++i)
            tj.src[dir * 5 + i] = Wlist[i] + (size_t)dir * WSQ;
    transpose_conv<<<dim3(24, 24, 10), 256, 0, stream>>>(tj, wtb);
    convert_x<<<dim3(NBT / (8 * 256)), 256, 0, stream>>>(x, xbb);
    convert_mu<<<dim3((MUN + 255) / 256), 256, 0, stream>>>(mu, muh, (int)MUN);

    const dim3 gridBig(BT / 128, CC / 128, 4);
    const dim3 gridOut(BT / 128, CC / 128, 1);

    for (int dir = 0; dir < 2; ++dir) {
        const float* muD = mu + (size_t)dir * 5 * CC;
        const u16* muhD = muh + (size_t)dir * 5 * CC;
        const u16* wt = wtb + (size_t)dir * 5 * WSQ;

        GB pb;
        pb.Wt[0] = wt + 0 * WSQ; pb.out[0] = rbuf; pb.mu[0] = muhD + 0 * CC; pb.act[0] = 0;
        pb.Wt[1] = wt + 1 * WSQ; pb.out[1] = kbuf; pb.mu[1] = muhD + 1 * CC; pb.act[1] = 0;
        pb.Wt[2] = wt + 2 * WSQ; pb.out[2] = vbuf; pb.mu[2] = muhD + 2 * CC; pb.act[2] = 0;
        pb.Wt[3] = wt + 3 * WSQ; pb.out[3] = gbuf; pb.mu[3] = muhD + 4 * CC; pb.act[3] = 1;
        gemm_mfma_big<<<gridBig, 512, 0, stream>>>(pb, nullptr, xbb, nullptr,
                                                   CC, CC, dir, 1);

        lora1_kernel<<<dim3(BT / 16), 256, 0, stream>>>(x, muD + 3 * CC,
                                                        dw1 + (size_t)dir * CC * LR,
                                                        lora, dir);
        gemm_kernel<<<dim3(BT / 64, CC / 64), 256, 0, stream>>>(
            lora, dw2 + (size_t)dir * LR * CC, wbias + (size_t)dir * CC,
            wwbuf, LR, CC);

        if (nch == 32) {
            scanA_kernel<32><<<dim3(32, HH, BBB), dim3(64), 0, stream>>>(
                kbuf, vbuf, wwbuf, SL, Pbuf);
            scanB_kernel<<<dim3(HH, BBB, 4), dim3(64), 0, stream>>>(SL, Pbuf, 32);
            scanC_kernel<32><<<dim3(32, HH, BBB), dim3(64), 0, stream>>>(
                rbuf, kbuf, vbuf, wwbuf, gbuf, SL, u, lnw, lnb, zb, dir);
        } else {
            scanA_kernel<64><<<dim3(16, HH, BBB), dim3(64), 0, stream>>>(
                kbuf, vbuf, wwbuf, SL, Pbuf);
            scanB_kernel<<<dim3(HH, BBB, 4), dim3(64), 0, stream>>>(SL, Pbuf, 16);
            scanC_kernel<64><<<dim3(16, HH, BBB), dim3(64), 0, stream>>>(
                rbuf, kbuf, vbuf, wwbuf, gbuf, SL, u, lnw, lnb, zb, dir);
        }

        GB po;
        po.Wt[0] = wt + 4 * WSQ; po.out[0] = out; po.mu[0] = nullptr;
        po.act[0] = (dir == 0) ? 4 : 5;
        po.Wt[1] = po.Wt[0]; po.out[1] = out; po.mu[1] = nullptr; po.act[1] = po.act[0];
        po.Wt[2] = po.Wt[0]; po.out[2] = out; po.mu[2] = nullptr; po.act[2] = po.act[0];
        po.Wt[3] = po.Wt[0]; po.out[3] = out; po.mu[3] = nullptr; po.act[3] = po.act[0];
        gemm_mfma_big<<<gridOut, 512, 0, stream>>>(po, zb, nullptr, mask,
                                                   CC, CC, dir, 0);
    }
}

// Round 10
// 480.659 us; speedup vs baseline: 1.5928x; 1.4465x over previous
//
#include <hip/hip_runtime.h>
#include <cstdint>
#include <cstddef>

// BiRWKV (RWKV-6 bidirectional time-mix), B=4 T=1024 C=768 H=12 D=64 LORA=64.
// Round 10: exact round-6 kernels (best measured: 512 us; GEMM spill-free at
// VGPR 44 — rounds 8/9's lambda-captured staging arrays went to scratch and
// regressed). One change: chunk ladder nch=64 (L=16) -> 32 -> 16 by ws_size,
// halving the scan's serial chain and doubling its occupancy.

#define HH   12
#define DD   64
#define CC   768
#define TT   1024
#define BBB  4
#define LR   64
#define BT   (BBB*TT)
#define WSQ  (CC*CC)

typedef unsigned short u16;
typedef _Float16 f16x8 __attribute__((ext_vector_type(8)));  // 8 f16 (4 VGPRs)
typedef float f32x4 __attribute__((ext_vector_type(4)));     // MFMA accumulator

__device__ __forceinline__ u16 f2h(float f) {
    const _Float16 h = (_Float16)f;
    return __builtin_bit_cast(u16, h);
}
__device__ __forceinline__ float h2f(u16 h) {
    return (float)__builtin_bit_cast(_Float16, h);
}

// pad_mask dtype detect (bool bytes vs int32 vs float32).
__device__ __forceinline__ float mask_val(const void* mp, int idx) {
    const unsigned char* b = (const unsigned char*)mp;
    const int i0 = ((const int*)mp)[0];
    if (i0 == 0x3f800000) {
        return ((const float*)mp)[idx] != 0.f ? 1.f : 0.f;
    }
    if ((b[1] | b[2] | b[3]) == 0) {
        return ((const int*)mp)[idx] != 0 ? 1.f : 0.f;
    }
    return b[idx] ? 1.f : 0.f;
}

// ---------------- prepass: weight transpose-convert, x convert ----------------
struct TP10 { const float* src[10]; };

__global__ __launch_bounds__(256)
void transpose_conv(TP10 tj, u16* __restrict__ dst)
{
    __shared__ float sh[32][33];
    const int j = blockIdx.z;
    const float* __restrict__ src = tj.src[j];
    u16* __restrict__ d = dst + (size_t)j * WSQ;
    const int n0 = blockIdx.x << 5, k0 = blockIdx.y << 5;
    const int tx = threadIdx.x & 31, ty = threadIdx.x >> 5;
    #pragma unroll
    for (int i = 0; i < 4; ++i)
        sh[ty + (i << 3)][tx] = src[(size_t)(k0 + ty + (i << 3)) * CC + n0 + tx];
    __syncthreads();
    #pragma unroll
    for (int i = 0; i < 4; ++i)
        d[(size_t)(n0 + ty + (i << 3)) * CC + k0 + tx] =
            f2h(sh[tx][ty + (i << 3)]);
}

__global__ __launch_bounds__(256)
void convert_x(const float* __restrict__ x, u16* __restrict__ xb)
{
    const size_t off = ((size_t)blockIdx.x * 256 + threadIdx.x) * 8;
    const float4 a = *reinterpret_cast<const float4*>(x + off);
    const float4 b = *reinterpret_cast<const float4*>(x + off + 4);
    uint4 w;
    w.x = (unsigned)f2h(a.x) | ((unsigned)f2h(a.y) << 16);
    w.y = (unsigned)f2h(a.z) | ((unsigned)f2h(a.w) << 16);
    w.z = (unsigned)f2h(b.x) | ((unsigned)f2h(b.y) << 16);
    w.w = (unsigned)f2h(b.z) | ((unsigned)f2h(b.w) << 16);
    *reinterpret_cast<uint4*>(xb + off) = w;
}

// ---------------- fp16 MFMA GEMM, 128x128 tile, 8 waves (round-6 form) --------
struct GB { const u16* Wt[4]; float* out[4]; const float* mu[4]; int act[4]; };

__global__ __launch_bounds__(512)
void gemm_mfma_big(GB p, const u16* __restrict__ Ab, const u16* __restrict__ xb,
                   const void* __restrict__ mask,
                   const int K, const int N, const int dir, const int mixA)
{
    const int j = blockIdx.z;
    const u16* __restrict__ Wt = p.Wt[j];
    float* __restrict__ out = p.out[j];
    const float* __restrict__ mu = p.mu[j];
    const int act = p.act[j];

    __shared__ __align__(16) u16 Als[128][72];
    __shared__ __align__(16) u16 Bls[128][72];
    const int tid = threadIdx.x;
    const int rowbase = blockIdx.x << 7;
    const int colbase = blockIdx.y << 7;
    const int lane = tid & 63;
    const int wid = tid >> 6;           // 0..7
    const int wr = (wid >> 2) << 6;     // 0 / 64
    const int wc = (wid & 3) << 5;      // 0,32,64,96
    const int lm = lane & 15;
    const int lk = (lane >> 4) << 3;    // 0,8,16,24

    f32x4 acc[4][2] = {};

    for (int k0 = 0; k0 < K; k0 += 64) {
        #pragma unroll
        for (int it = 0; it < 2; ++it) {
            const int c   = tid + (it << 9);
            const int row = c >> 3;
            const int kq  = (c & 7) << 3;
            *reinterpret_cast<uint4*>(&Bls[row][kq]) =
                *reinterpret_cast<const uint4*>(
                    Wt + (size_t)(colbase + row) * K + k0 + kq);
            if (mixA) {
                const int s  = rowbase + row;
                const int bb = s >> 10, ts = s & (TT - 1);
                const int t  = dir ? (TT - 1 - ts) : ts;
                const int tp = dir ? (t + 1) : (t - 1);
                const uint4 xa4 = *reinterpret_cast<const uint4*>(
                    xb + (size_t)(bb * TT + t) * CC + k0 + kq);
                uint4 xp4 = make_uint4(0u, 0u, 0u, 0u);
                if (ts > 0)
                    xp4 = *reinterpret_cast<const uint4*>(
                        xb + (size_t)(bb * TT + tp) * CC + k0 + kq);
                const u16* as = reinterpret_cast<const u16*>(&xa4);
                const u16* ps = reinterpret_cast<const u16*>(&xp4);
                const float4 m0 = *reinterpret_cast<const float4*>(mu + k0 + kq);
                const float4 m1 = *reinterpret_cast<const float4*>(mu + k0 + kq + 4);
                const float mm[8] = {m0.x, m0.y, m0.z, m0.w,
                                     m1.x, m1.y, m1.z, m1.w};
                uint4 w;
                unsigned rr[4];
                #pragma unroll
                for (int q = 0; q < 4; ++q) {
                    const float a0 = h2f(as[2 * q]);
                    const float a1 = h2f(as[2 * q + 1]);
                    const float p0 = h2f(ps[2 * q]);
                    const float p1 = h2f(ps[2 * q + 1]);
                    const float v0 = fmaf(p0 - a0, mm[2 * q], a0);
                    const float v1 = fmaf(p1 - a1, mm[2 * q + 1], a1);
                    rr[q] = (unsigned)f2h(v0) | ((unsigned)f2h(v1) << 16);
                }
                w.x = rr[0]; w.y = rr[1]; w.z = rr[2]; w.w = rr[3];
                *reinterpret_cast<uint4*>(&Als[row][kq]) = w;
            } else {
                *reinterpret_cast<uint4*>(&Als[row][kq]) =
                    *reinterpret_cast<const uint4*>(
                        Ab + (size_t)(rowbase + row) * K + k0 + kq);
            }
        }
        __syncthreads();
        #pragma unroll
        for (int ks = 0; ks < 2; ++ks) {
            const int ko = (ks << 5) + lk;
            f16x8 av[4], bv[2];
            #pragma unroll
            for (int mi = 0; mi < 4; ++mi)
                av[mi] = *reinterpret_cast<const f16x8*>(&Als[wr + mi * 16 + lm][ko]);
            #pragma unroll
            for (int ni = 0; ni < 2; ++ni)
                bv[ni] = *reinterpret_cast<const f16x8*>(&Bls[wc + ni * 16 + lm][ko]);
            #pragma unroll
            for (int mi = 0; mi < 4; ++mi)
                #pragma unroll
                for (int ni = 0; ni < 2; ++ni)
                    acc[mi][ni] = __builtin_amdgcn_mfma_f32_16x16x32_f16(
                        av[mi], bv[ni], acc[mi][ni], 0, 0, 0);
        }
        __syncthreads();
    }

    #pragma unroll
    for (int mi = 0; mi < 4; ++mi) {
        #pragma unroll
        for (int r = 0; r < 4; ++r) {
            const int srow = rowbase + wr + mi * 16 + ((lane >> 4) << 2) + r;
            float v0 = acc[mi][0][r];
            float v1 = acc[mi][1][r];
            if (act == 1) {
                v0 = v0 / (1.f + expf(-v0));
                v1 = v1 / (1.f + expf(-v1));
            }
            const int col = colbase + wc + lm;
            if (act <= 1) {
                out[(size_t)srow * N + col]      = v0;
                out[(size_t)srow * N + col + 16] = v1;
            } else {
                const int b2  = srow >> 10;
                const int ts2 = srow & (TT - 1);
                const int t2  = dir ? (TT - 1 - ts2) : ts2;
                float* op = out + (size_t)(b2 * TT + t2) * CC + col;
                if (act == 4) {
                    op[0]  = v0;
                    op[16] = v1;
                } else {
                    const float mv = mask_val(mask, b2 * TT + t2);
                    op[0]  = (op[0]  + v0) * mv;
                    op[16] = (op[16] + v1) * mv;
                }
            }
        }
    }
}

// ---------------- fp32 lora1 (x-mix @ dw1, tanh), 16-row tiles ----------------
__global__ __launch_bounds__(256)
void lora1_kernel(const float* __restrict__ x, const float* __restrict__ mu,
                  const float* __restrict__ dw1, float* __restrict__ out,
                  const int dir)
{
    __shared__ float As[16][68];
    __shared__ float Bs[64][68];
    const int tid = threadIdx.x;
    const int rowbase = blockIdx.x << 4;

    const int arow = tid >> 4;
    const int akq  = (tid & 15) << 2;
    const int s  = rowbase + arow;
    const int bb = s >> 10, ts = s & (TT - 1);
    const int t  = dir ? (TT - 1 - ts) : ts;
    const int tp = dir ? (t + 1) : (t - 1);

    const int c0 = tid & 63;
    const int r4 = tid >> 6;

    float acc[4] = {0.f, 0.f, 0.f, 0.f};

    for (int k0 = 0; k0 < CC; k0 += 64) {
        {
            const int c = k0 + akq;
            const float4 xa = *reinterpret_cast<const float4*>(
                x + (size_t)(bb * TT + t) * CC + c);
            float4 xp = make_float4(0.f, 0.f, 0.f, 0.f);
            if (ts > 0)
                xp = *reinterpret_cast<const float4*>(
                    x + (size_t)(bb * TT + tp) * CC + c);
            const float4 m4 = *reinterpret_cast<const float4*>(mu + c);
            float4 va;
            va.x = fmaf(xp.x - xa.x, m4.x, xa.x);
            va.y = fmaf(xp.y - xa.y, m4.y, xa.y);
            va.z = fmaf(xp.z - xa.z, m4.z, xa.z);
            va.w = fmaf(xp.w - xa.w, m4.w, xa.w);
            *reinterpret_cast<float4*>(&As[arow][akq]) = va;
        }
        #pragma unroll
        for (int it = 0; it < 4; ++it) {
            const int c2 = tid + (it << 8);
            const int brow = c2 >> 4, bcol = (c2 & 15) << 2;
            *reinterpret_cast<float4*>(&Bs[brow][bcol]) =
                *reinterpret_cast<const float4*>(
                    dw1 + (size_t)(k0 + brow) * LR + bcol);
        }
        __syncthreads();
        #pragma unroll
        for (int k4 = 0; k4 < 16; ++k4) {
            float bv[4];
            #pragma unroll
            for (int q = 0; q < 4; ++q) bv[q] = Bs[(k4 << 2) + q][c0];
            #pragma unroll
            for (int i = 0; i < 4; ++i) {
                const float4 a4 = *reinterpret_cast<const float4*>(
                    &As[r4 + (i << 2)][k4 << 2]);
                acc[i] = fmaf(a4.x, bv[0], acc[i]);
                acc[i] = fmaf(a4.y, bv[1], acc[i]);
                acc[i] = fmaf(a4.z, bv[2], acc[i]);
                acc[i] = fmaf(a4.w, bv[3], acc[i]);
            }
        }
        __syncthreads();
    }
    #pragma unroll
    for (int i = 0; i < 4; ++i)
        out[(size_t)(rowbase + r4 + (i << 2)) * LR + c0] = tanhf(acc[i]);
}

// ---------------- fp32 GEMM (lora2: decay exp(-exp)) ----------------
__global__ __launch_bounds__(256)
void gemm_kernel(const float* __restrict__ Ap, const float* __restrict__ W,
                 const float* __restrict__ bias, float* __restrict__ out,
                 const int K, const int N)
{
    __shared__ float As[16][68];
    __shared__ float Bs[16][68];
    const int tid = threadIdx.x;
    const int rowbase = blockIdx.x << 6;
    const int colbase = blockIdx.y << 6;
    const int ty = tid >> 4, tx = tid & 15;
    const int am = tid >> 2;
    const int aq = tid & 3;
    const int s  = rowbase + am;
    const int bk = tid >> 4;
    const int bn = (tid & 15) << 2;

    float acc[4][4];
    #pragma unroll
    for (int i = 0; i < 4; ++i)
        #pragma unroll
        for (int j = 0; j < 4; ++j) acc[i][j] = 0.f;

    for (int k0 = 0; k0 < K; k0 += 16) {
        const float4 va = *reinterpret_cast<const float4*>(
            Ap + (size_t)s * K + k0 + (aq << 2));
        const float4 vb = *reinterpret_cast<const float4*>(
            W + (size_t)(k0 + bk) * N + colbase + bn);
        As[(aq << 2) + 0][am] = va.x;
        As[(aq << 2) + 1][am] = va.y;
        As[(aq << 2) + 2][am] = va.z;
        As[(aq << 2) + 3][am] = va.w;
        *reinterpret_cast<float4*>(&Bs[bk][bn]) = vb;
        __syncthreads();
        #pragma unroll
        for (int kk = 0; kk < 16; ++kk) {
            const float4 a  = *reinterpret_cast<const float4*>(&As[kk][ty << 2]);
            const float4 bv = *reinterpret_cast<const float4*>(&Bs[kk][tx << 2]);
            const float av[4]  = {a.x, a.y, a.z, a.w};
            const float bvv[4] = {bv.x, bv.y, bv.z, bv.w};
            #pragma unroll
            for (int i = 0; i < 4; ++i)
                #pragma unroll
                for (int j = 0; j < 4; ++j)
                    acc[i][j] = fmaf(av[i], bvv[j], acc[i][j]);
        }
        __syncthreads();
    }

    #pragma unroll
    for (int i = 0; i < 4; ++i) {
        const int srow = rowbase + (ty << 2) + i;
        const int ncol = colbase + (tx << 2);
        float v[4];
        #pragma unroll
        for (int j = 0; j < 4; ++j)
            v[j] = expf(-expf(acc[i][j] + bias[ncol + j]));
        *reinterpret_cast<float4*>(out + (size_t)srow * N + ncol) =
            make_float4(v[0], v[1], v[2], v[3]);
    }
}

// ---------------- chunked scan (A/B/C), round-6 forms ----------------
template<int L>
__global__ __launch_bounds__(64)
void scanA_kernel(const float* __restrict__ kbuf, const float* __restrict__ vbuf,
                  const float* __restrict__ wbuf,
                  float* __restrict__ SL, float* __restrict__ Pbuf)
{
    __shared__ float lk[L * DD], lw[L * DD], lv[L * DD];
    const int c = blockIdx.x, h = blockIdx.y, b = blockIdx.z;
    const int e = threadIdx.x;
    const int rowq = e >> 4;
    const int col  = (e & 15) << 2;

    const size_t gbase = (size_t)(b * TT + c * L) * CC + h * DD;
    #pragma unroll
    for (int r4 = 0; r4 < L / 4; ++r4) {
        const int row = (r4 << 2) + rowq;
        const size_t ga = gbase + (size_t)row * CC + col;
        *reinterpret_cast<float4*>(&lk[row * DD + col]) =
            *reinterpret_cast<const float4*>(kbuf + ga);
        *reinterpret_cast<float4*>(&lw[row * DD + col]) =
            *reinterpret_cast<const float4*>(wbuf + ga);
        *reinterpret_cast<float4*>(&lv[row * DD + col]) =
            *reinterpret_cast<const float4*>(vbuf + ga);
    }
    __syncthreads();

    float S[DD];
    #pragma unroll
    for (int d = 0; d < DD; ++d) S[d] = 0.f;
    float P = 1.f;

    for (int t = 0; t < L; ++t) {
        const float ve = lv[t * DD + e];
        P *= lw[t * DD + e];
        #pragma unroll
        for (int d4 = 0; d4 < 16; ++d4) {
            const float4 k4 = *reinterpret_cast<const float4*>(&lk[t * DD + (d4 << 2)]);
            const float4 w4 = *reinterpret_cast<const float4*>(&lw[t * DD + (d4 << 2)]);
            S[(d4 << 2) + 0] = fmaf(w4.x, S[(d4 << 2) + 0], k4.x * ve);
            S[(d4 << 2) + 1] = fmaf(w4.y, S[(d4 << 2) + 1], k4.y * ve);
            S[(d4 << 2) + 2] = fmaf(w4.z, S[(d4 << 2) + 2], k4.z * ve);
            S[(d4 << 2) + 3] = fmaf(w4.w, S[(d4 << 2) + 3], k4.w * ve);
        }
    }

    float* slot = SL + (size_t)((c * BBB + b) * HH + h) * DD * DD;
    #pragma unroll
    for (int d = 0; d < DD; ++d) slot[d * DD + e] = S[d];
    Pbuf[(size_t)((c * BBB + b) * HH + h) * DD + e] = P;
}

// Pass B: sequential over chunks, depth-1 register prefetch.
__global__ __launch_bounds__(64)
void scanB_kernel(float* __restrict__ SL, const float* __restrict__ Pbuf,
                  const int nch)
{
    const int h = blockIdx.x, b = blockIdx.y, dg = blockIdx.z;
    const int e = threadIdx.x;
    const size_t doff = (size_t)dg * 16 * DD;

    float S[16];
    #pragma unroll
    for (int i = 0; i < 16; ++i) S[i] = 0.f;

    float sl[16], pp[16];
    {
        const float* s0 = SL + (size_t)(b * HH + h) * DD * DD + doff;
        const float* p0 = Pbuf + (size_t)(b * HH + h) * DD + dg * 16;
        #pragma unroll
        for (int i = 0; i < 16; ++i) { sl[i] = s0[i * DD + e]; pp[i] = p0[i]; }
    }
    for (int c = 0; c < nch; ++c) {
        float sl2[16], pp2[16];
        if (c + 1 < nch) {
            const float* s1 = SL + (size_t)(((c + 1) * BBB + b) * HH + h) * DD * DD + doff;
            const float* p1 = Pbuf + (size_t)(((c + 1) * BBB + b) * HH + h) * DD + dg * 16;
            #pragma unroll
            for (int i = 0; i < 16; ++i) { sl2[i] = s1[i * DD + e]; pp2[i] = p1[i]; }
        }
        float* sc = SL + (size_t)((c * BBB + b) * HH + h) * DD * DD + doff;
        #pragma unroll
        for (int i = 0; i < 16; ++i) {
            S[i] = fmaf(pp[i], S[i], sl[i]);
            sc[i * DD + e] = S[i];
        }
        #pragma unroll
        for (int i = 0; i < 16; ++i) { sl[i] = sl2[i]; pp[i] = pp2[i]; }
    }
}

template<int L>
__global__ __launch_bounds__(64)
void scanC_kernel(const float* __restrict__ rbuf, const float* __restrict__ kbuf,
                  const float* __restrict__ vbuf, const float* __restrict__ wbuf,
                  const float* __restrict__ gbuf, const float* __restrict__ SL,
                  const float* __restrict__ u, const float* __restrict__ lnw,
                  const float* __restrict__ lnb, u16* __restrict__ zb,
                  const int dir)
{
    __shared__ float lr[L * DD], lk[L * DD], lw[L * DD];
    const int c = blockIdx.x, h = blockIdx.y, b = blockIdx.z;
    const int e = threadIdx.x;
    const int rowq = e >> 4;
    const int col  = (e & 15) << 2;

    const size_t gbase = (size_t)(b * TT + c * L) * CC + h * DD;
    #pragma unroll
    for (int r4 = 0; r4 < L / 4; ++r4) {
        const int row = (r4 << 2) + rowq;
        const size_t ga = gbase + (size_t)row * CC + col;
        *reinterpret_cast<float4*>(&lr[row * DD + col]) =
            *reinterpret_cast<const float4*>(rbuf + ga);
        *reinterpret_cast<float4*>(&lk[row * DD + col]) =
            *reinterpret_cast<const float4*>(kbuf + ga);
        *reinterpret_cast<float4*>(&lw[row * DD + col]) =
            *reinterpret_cast<const float4*>(wbuf + ga);
    }
    __syncthreads();

    const float ue = u[(size_t)(dir * HH + h) * DD + e];
    const float gw = lnw[dir * CC + h * DD + e];
    const float gb = lnb[dir * CC + h * DD + e];

    float S[DD];
    if (c == 0) {
        #pragma unroll
        for (int d = 0; d < DD; ++d) S[d] = 0.f;
    } else {
        const float* slot = SL + (size_t)(((c - 1) * BBB + b) * HH + h) * DD * DD;
        #pragma unroll
        for (int d = 0; d < DD; ++d) S[d] = slot[d * DD + e];
    }

    float ve = vbuf[gbase + e];
    float ge = gbuf[gbase + e];
    for (int t = 0; t < L; ++t) {
        float ve2 = 0.f, ge2 = 0.f;
        if (t + 1 < L) {
            ve2 = vbuf[gbase + (size_t)(t + 1) * CC + e];
            ge2 = gbuf[gbase + (size_t)(t + 1) * CC + e];
        }
        float coef = lr[t * DD + e] * ue * lk[t * DD + e];
        #pragma unroll
        for (int off = 32; off > 0; off >>= 1) coef += __shfl_xor(coef, off);

        float y0 = 0.f, y1 = 0.f, y2 = 0.f, y3 = 0.f;
        #pragma unroll
        for (int d4 = 0; d4 < 16; ++d4) {
            const float4 r4 = *reinterpret_cast<const float4*>(&lr[t * DD + (d4 << 2)]);
            const float4 k4 = *reinterpret_cast<const float4*>(&lk[t * DD + (d4 << 2)]);
            const float4 w4 = *reinterpret_cast<const float4*>(&lw[t * DD + (d4 << 2)]);
            y0 = fmaf(r4.x, S[(d4 << 2) + 0], y0);
            y1 = fmaf(r4.y, S[(d4 << 2) + 1], y1);
            y2 = fmaf(r4.z, S[(d4 << 2) + 2], y2);
            y3 = fmaf(r4.w, S[(d4 << 2) + 3], y3);
            S[(d4 << 2) + 0] = fmaf(w4.x, S[(d4 << 2) + 0], k4.x * ve);
            S[(d4 << 2) + 1] = fmaf(w4.y, S[(d4 << 2) + 1], k4.y * ve);
            S[(d4 << 2) + 2] = fmaf(w4.z, S[(d4 << 2) + 2], k4.z * ve);
            S[(d4 << 2) + 3] = fmaf(w4.w, S[(d4 << 2) + 3], k4.w * ve);
        }
        float y = ((y0 + y1) + (y2 + y3)) + coef * ve;

        float sum = y, sq = y * y;
        #pragma unroll
        for (int off = 32; off > 0; off >>= 1) {
            sum += __shfl_xor(sum, off);
            sq  += __shfl_xor(sq, off);
        }
        const float mean = sum * (1.f / 64.f);
        const float var  = fmaf(-mean, mean, sq * (1.f / 64.f));
        const float yn   = (y - mean) * rsqrtf(var + 1e-5f) * gw + gb;
        zb[gbase + (size_t)t * CC + e] = f2h(yn * ge);
        ve = ve2;
        ge = ge2;
    }
}

extern "C" void kernel_launch(void* const* d_in, const int* in_sizes, int n_in,
                              void* d_out, int out_size, void* d_ws, size_t ws_size,
                              hipStream_t stream)
{
    const float* x     = (const float*)d_in[0];
    const void*  mask  = d_in[1];
    const float* mu    = (const float*)d_in[2];
    const float* wbias = (const float*)d_in[3];
    const float* dw1   = (const float*)d_in[4];
    const float* dw2   = (const float*)d_in[5];
    const float* u     = (const float*)d_in[6];
    const float* Wr    = (const float*)d_in[7];
    const float* Wk    = (const float*)d_in[8];
    const float* Wv    = (const float*)d_in[9];
    const float* Wg    = (const float*)d_in[10];
    const float* Wo    = (const float*)d_in[11];
    const float* lnw   = (const float*)d_in[12];
    const float* lnb   = (const float*)d_in[13];
    float* out = (float*)d_out;

    float* ws = (float*)d_ws;
    const size_t NBT = (size_t)BT * CC;

    auto need_bytes = [&](int nch) -> size_t {
        const size_t fl = 5 * NBT + (size_t)BT * LR
                        + (size_t)nch * BBB * HH * DD * DD
                        + (size_t)nch * BBB * HH * DD;
        const size_t hw = 2 * NBT + (size_t)10 * WSQ;
        return fl * 4 + hw * 2;
    };
    const int nch = (ws_size >= need_bytes(64)) ? 64
                  : (ws_size >= need_bytes(32)) ? 32 : 16;

    float* rbuf  = ws;
    float* kbuf  = rbuf  + NBT;
    float* vbuf  = kbuf  + NBT;
    float* wwbuf = vbuf  + NBT;
    float* gbuf  = wwbuf + NBT;
    float* lora  = gbuf  + NBT;
    float* SL    = lora  + (size_t)BT * LR;
    float* Pbuf  = SL    + (size_t)nch * BBB * HH * DD * DD;
    u16*   zb    = (u16*)(Pbuf + (size_t)nch * BBB * HH * DD);
    u16*   xbb   = zb + NBT;
    u16*   wtb   = xbb + NBT;

    TP10 tj;
    const float* Wlist[5] = {Wr, Wk, Wv, Wg, Wo};
    for (int dir = 0; dir < 2; ++dir)
        for (int i = 0; i < 5; ++i)
            tj.src[dir * 5 + i] = Wlist[i] + (size_t)dir * WSQ;
    transpose_conv<<<dim3(24, 24, 10), 256, 0, stream>>>(tj, wtb);
    convert_x<<<dim3(NBT / (8 * 256)), 256, 0, stream>>>(x, xbb);

    const dim3 gridBig(BT / 128, CC / 128, 4);
    const dim3 gridOut(BT / 128, CC / 128, 1);

    for (int dir = 0; dir < 2; ++dir) {
        const float* muD = mu + (size_t)dir * 5 * CC;
        const u16* wt = wtb + (size_t)dir * 5 * WSQ;

        GB pb;
        pb.Wt[0] = wt + 0 * WSQ; pb.out[0] = rbuf; pb.mu[0] = muD + 0 * CC; pb.act[0] = 0;
        pb.Wt[1] = wt + 1 * WSQ; pb.out[1] = kbuf; pb.mu[1] = muD + 1 * CC; pb.act[1] = 0;
        pb.Wt[2] = wt + 2 * WSQ; pb.out[2] = vbuf; pb.mu[2] = muD + 2 * CC; pb.act[2] = 0;
        pb.Wt[3] = wt + 3 * WSQ; pb.out[3] = gbuf; pb.mu[3] = muD + 4 * CC; pb.act[3] = 1;
        gemm_mfma_big<<<gridBig, 512, 0, stream>>>(pb, nullptr, xbb, nullptr,
                                                   CC, CC, dir, 1);

        lora1_kernel<<<dim3(BT / 16), 256, 0, stream>>>(x, muD + 3 * CC,
                                                        dw1 + (size_t)dir * CC * LR,
                                                        lora, dir);
        gemm_kernel<<<dim3(BT / 64, CC / 64), 256, 0, stream>>>(
            lora, dw2 + (size_t)dir * LR * CC, wbias + (size_t)dir * CC,
            wwbuf, LR, CC);

        if (nch == 64) {
            scanA_kernel<16><<<dim3(64, HH, BBB), dim3(64), 0, stream>>>(
                kbuf, vbuf, wwbuf, SL, Pbuf);
            scanB_kernel<<<dim3(HH, BBB, 4), dim3(64), 0, stream>>>(SL, Pbuf, 64);
            scanC_kernel<16><<<dim3(64, HH, BBB), dim3(64), 0, stream>>>(
                rbuf, kbuf, vbuf, wwbuf, gbuf, SL, u, lnw, lnb, zb, dir);
        } else if (nch == 32) {
            scanA_kernel<32><<<dim3(32, HH, BBB), dim3(64), 0, stream>>>(
                kbuf, vbuf, wwbuf, SL, Pbuf);
            scanB_kernel<<<dim3(HH, BBB, 4), dim3(64), 0, stream>>>(SL, Pbuf, 32);
            scanC_kernel<32><<<dim3(32, HH, BBB), dim3(64), 0, stream>>>(
                rbuf, kbuf, vbuf, wwbuf, gbuf, SL, u, lnw, lnb, zb, dir);
        } else {
            scanA_kernel<64><<<dim3(16, HH, BBB), dim3(64), 0, stream>>>(
                kbuf, vbuf, wwbuf, SL, Pbuf);
            scanB_kernel<<<dim3(HH, BBB, 4), dim3(64), 0, stream>>>(SL, Pbuf, 16);
            scanC_kernel<64><<<dim3(16, HH, BBB), dim3(64), 0, stream>>>(
                rbuf, kbuf, vbuf, wwbuf, gbuf, SL, u, lnw, lnb, zb, dir);
        }

        GB po;
        po.Wt[0] = wt + 4 * WSQ; po.out[0] = out; po.mu[0] = nullptr;
        po.act[0] = (dir == 0) ? 4 : 5;
        po.Wt[1] = po.Wt[0]; po.out[1] = out; po.mu[1] = nullptr; po.act[1] = po.act[0];
        po.Wt[2] = po.Wt[0]; po.out[2] = out; po.mu[2] = nullptr; po.act[2] = po.act[0];
        po.Wt[3] = po.Wt[0]; po.out[3] = out; po.mu[3] = nullptr; po.act[3] = po.act[0];
        gemm_mfma_big<<<gridOut, 512, 0, stream>>>(po, zb, nullptr, mask,
                                                   CC, CC, dir, 0);
    }
}

// Round 11
// 475.385 us; speedup vs baseline: 1.6105x; 1.0111x over previous
//
#include <hip/hip_runtime.h>
#include <cstdint>
#include <cstddef>

// BiRWKV (RWKV-6 bidirectional time-mix), B=4 T=1024 C=768 H=12 D=64 LORA=64.
// Round 11: token-shift mix defactored out of the GEMM into mix4_kernel
// (packed-fp16, once per dir — the GEMM grid recomputed it 6x redundantly and
// it dominated VALUBusy). GEMM is now pure fp16 MFMA with per-slot A pointers.
// Scan (nch=64 ladder), lora path, numerics unchanged from round 10 (480 us).

#define HH   12
#define DD   64
#define CC   768
#define TT   1024
#define BBB  4
#define LR   64
#define BT   (BBB*TT)
#define WSQ  (CC*CC)

typedef unsigned short u16;
typedef _Float16 f16x8 __attribute__((ext_vector_type(8)));  // 8 f16 (4 VGPRs)
typedef float f32x4 __attribute__((ext_vector_type(4)));     // MFMA accumulator

__device__ __forceinline__ u16 f2h(float f) {
    const _Float16 h = (_Float16)f;
    return __builtin_bit_cast(u16, h);
}
__device__ __forceinline__ float h2f(u16 h) {
    return (float)__builtin_bit_cast(_Float16, h);
}

// pad_mask dtype detect (bool bytes vs int32 vs float32).
__device__ __forceinline__ float mask_val(const void* mp, int idx) {
    const unsigned char* b = (const unsigned char*)mp;
    const int i0 = ((const int*)mp)[0];
    if (i0 == 0x3f800000) {
        return ((const float*)mp)[idx] != 0.f ? 1.f : 0.f;
    }
    if ((b[1] | b[2] | b[3]) == 0) {
        return ((const int*)mp)[idx] != 0 ? 1.f : 0.f;
    }
    return b[idx] ? 1.f : 0.f;
}

// ---------------- prepass: weight transpose-convert, x/mu convert -------------
struct TP10 { const float* src[10]; };

__global__ __launch_bounds__(256)
void transpose_conv(TP10 tj, u16* __restrict__ dst)
{
    __shared__ float sh[32][33];
    const int j = blockIdx.z;
    const float* __restrict__ src = tj.src[j];
    u16* __restrict__ d = dst + (size_t)j * WSQ;
    const int n0 = blockIdx.x << 5, k0 = blockIdx.y << 5;
    const int tx = threadIdx.x & 31, ty = threadIdx.x >> 5;
    #pragma unroll
    for (int i = 0; i < 4; ++i)
        sh[ty + (i << 3)][tx] = src[(size_t)(k0 + ty + (i << 3)) * CC + n0 + tx];
    __syncthreads();
    #pragma unroll
    for (int i = 0; i < 4; ++i)
        d[(size_t)(n0 + ty + (i << 3)) * CC + k0 + tx] =
            f2h(sh[tx][ty + (i << 3)]);
}

__global__ __launch_bounds__(256)
void convert_x(const float* __restrict__ x, u16* __restrict__ xb)
{
    const size_t off = ((size_t)blockIdx.x * 256 + threadIdx.x) * 8;
    const float4 a = *reinterpret_cast<const float4*>(x + off);
    const float4 b = *reinterpret_cast<const float4*>(x + off + 4);
    uint4 w;
    w.x = (unsigned)f2h(a.x) | ((unsigned)f2h(a.y) << 16);
    w.y = (unsigned)f2h(a.z) | ((unsigned)f2h(a.w) << 16);
    w.z = (unsigned)f2h(b.x) | ((unsigned)f2h(b.y) << 16);
    w.w = (unsigned)f2h(b.z) | ((unsigned)f2h(b.w) << 16);
    *reinterpret_cast<uint4*>(xb + off) = w;
}

__global__ __launch_bounds__(256)
void convert_mu(const float* __restrict__ mu, u16* __restrict__ muh, int n)
{
    const int i = blockIdx.x * 256 + threadIdx.x;
    if (i < n) muh[i] = f2h(mu[i]);
}

// ---------------- mix prepass: 4 mixed fp16 A-buffers, scan-row order ---------
// out[j][s*CC + c] = lerp(x[t], x[tprev], mu_j)  (packed fp16; j: r,k,v,g)
__global__ __launch_bounds__(256)
void mix4_kernel(const u16* __restrict__ xb, const u16* __restrict__ muh,
                 u16* __restrict__ o0, u16* __restrict__ o1,
                 u16* __restrict__ o2, u16* __restrict__ o3, const int dir)
{
    const int j = blockIdx.y;
    const int idx = blockIdx.x * 256 + threadIdx.x;     // one uint4 (8 elems)
    const int s = idx / 96;                             // CC/8 = 96
    const int c = (idx - s * 96) << 3;
    const int b = s >> 10, ts = s & (TT - 1);
    const int t = dir ? (TT - 1 - ts) : ts;
    const int tp = dir ? (t + 1) : (t - 1);
    const int musel = (j == 3) ? 4 : j;

    const uint4 xa4 = *reinterpret_cast<const uint4*>(
        xb + (size_t)(b * TT + t) * CC + c);
    uint4 xp4 = make_uint4(0u, 0u, 0u, 0u);
    if (ts > 0)
        xp4 = *reinterpret_cast<const uint4*>(
            xb + (size_t)(b * TT + tp) * CC + c);
    const uint4 m4 = *reinterpret_cast<const uint4*>(muh + musel * CC + c);

    const f16x8 xa = __builtin_bit_cast(f16x8, xa4);
    const f16x8 xp = __builtin_bit_cast(f16x8, xp4);
    const f16x8 mm = __builtin_bit_cast(f16x8, m4);
    const f16x8 res = (xp - xa) * mm + xa;              // v_pk_* fp16

    u16* __restrict__ dst = (j == 0) ? o0 : (j == 1) ? o1 : (j == 2) ? o2 : o3;
    *reinterpret_cast<uint4*>(dst + (size_t)s * CC + c) =
        __builtin_bit_cast(uint4, res);
}

// ---------------- fp16 MFMA GEMM, 128x128 tile, 8 waves -----------------------
// Per-slot A/B/out; mixA=1 is the in-GEMM fallback (used only if ws too small).
struct GB { const u16* Wt[4]; const u16* Ab[4]; float* out[4];
            const float* mu[4]; int act[4]; };

__global__ __launch_bounds__(512)
void gemm_mfma_big(GB p, const u16* __restrict__ xb,
                   const void* __restrict__ mask,
                   const int K, const int N, const int dir, const int mixA)
{
    const int j = blockIdx.z;
    const u16* __restrict__ Wt = p.Wt[j];
    const u16* __restrict__ Ab = p.Ab[j];
    float* __restrict__ out = p.out[j];
    const float* __restrict__ mu = p.mu[j];
    const int act = p.act[j];

    __shared__ __align__(16) u16 Als[128][72];
    __shared__ __align__(16) u16 Bls[128][72];
    const int tid = threadIdx.x;
    const int rowbase = blockIdx.x << 7;
    const int colbase = blockIdx.y << 7;
    const int lane = tid & 63;
    const int wid = tid >> 6;           // 0..7
    const int wr = (wid >> 2) << 6;     // 0 / 64
    const int wc = (wid & 3) << 5;      // 0,32,64,96
    const int lm = lane & 15;
    const int lk = (lane >> 4) << 3;    // 0,8,16,24

    f32x4 acc[4][2] = {};

    for (int k0 = 0; k0 < K; k0 += 64) {
        #pragma unroll
        for (int it = 0; it < 2; ++it) {
            const int c   = tid + (it << 9);
            const int row = c >> 3;
            const int kq  = (c & 7) << 3;
            *reinterpret_cast<uint4*>(&Bls[row][kq]) =
                *reinterpret_cast<const uint4*>(
                    Wt + (size_t)(colbase + row) * K + k0 + kq);
            if (mixA) {
                const int s  = rowbase + row;
                const int bb = s >> 10, ts = s & (TT - 1);
                const int t  = dir ? (TT - 1 - ts) : ts;
                const int tp = dir ? (t + 1) : (t - 1);
                const uint4 xa4 = *reinterpret_cast<const uint4*>(
                    xb + (size_t)(bb * TT + t) * CC + k0 + kq);
                uint4 xp4 = make_uint4(0u, 0u, 0u, 0u);
                if (ts > 0)
                    xp4 = *reinterpret_cast<const uint4*>(
                        xb + (size_t)(bb * TT + tp) * CC + k0 + kq);
                const u16* as = reinterpret_cast<const u16*>(&xa4);
                const u16* ps = reinterpret_cast<const u16*>(&xp4);
                const float4 m0 = *reinterpret_cast<const float4*>(mu + k0 + kq);
                const float4 m1 = *reinterpret_cast<const float4*>(mu + k0 + kq + 4);
                const float mm[8] = {m0.x, m0.y, m0.z, m0.w,
                                     m1.x, m1.y, m1.z, m1.w};
                uint4 w;
                unsigned rr[4];
                #pragma unroll
                for (int q = 0; q < 4; ++q) {
                    const float a0 = h2f(as[2 * q]);
                    const float a1 = h2f(as[2 * q + 1]);
                    const float p0 = h2f(ps[2 * q]);
                    const float p1 = h2f(ps[2 * q + 1]);
                    const float v0 = fmaf(p0 - a0, mm[2 * q], a0);
                    const float v1 = fmaf(p1 - a1, mm[2 * q + 1], a1);
                    rr[q] = (unsigned)f2h(v0) | ((unsigned)f2h(v1) << 16);
                }
                w.x = rr[0]; w.y = rr[1]; w.z = rr[2]; w.w = rr[3];
                *reinterpret_cast<uint4*>(&Als[row][kq]) = w;
            } else {
                *reinterpret_cast<uint4*>(&Als[row][kq]) =
                    *reinterpret_cast<const uint4*>(
                        Ab + (size_t)(rowbase + row) * K + k0 + kq);
            }
        }
        __syncthreads();
        #pragma unroll
        for (int ks = 0; ks < 2; ++ks) {
            const int ko = (ks << 5) + lk;
            f16x8 av[4], bv[2];
            #pragma unroll
            for (int mi = 0; mi < 4; ++mi)
                av[mi] = *reinterpret_cast<const f16x8*>(&Als[wr + mi * 16 + lm][ko]);
            #pragma unroll
            for (int ni = 0; ni < 2; ++ni)
                bv[ni] = *reinterpret_cast<const f16x8*>(&Bls[wc + ni * 16 + lm][ko]);
            #pragma unroll
            for (int mi = 0; mi < 4; ++mi)
                #pragma unroll
                for (int ni = 0; ni < 2; ++ni)
                    acc[mi][ni] = __builtin_amdgcn_mfma_f32_16x16x32_f16(
                        av[mi], bv[ni], acc[mi][ni], 0, 0, 0);
        }
        __syncthreads();
    }

    #pragma unroll
    for (int mi = 0; mi < 4; ++mi) {
        #pragma unroll
        for (int r = 0; r < 4; ++r) {
            const int srow = rowbase + wr + mi * 16 + ((lane >> 4) << 2) + r;
            float v0 = acc[mi][0][r];
            float v1 = acc[mi][1][r];
            if (act == 1) {
                v0 = v0 / (1.f + expf(-v0));
                v1 = v1 / (1.f + expf(-v1));
            }
            const int col = colbase + wc + lm;
            if (act <= 1) {
                out[(size_t)srow * N + col]      = v0;
                out[(size_t)srow * N + col + 16] = v1;
            } else {
                const int b2  = srow >> 10;
                const int ts2 = srow & (TT - 1);
                const int t2  = dir ? (TT - 1 - ts2) : ts2;
                float* op = out + (size_t)(b2 * TT + t2) * CC + col;
                if (act == 4) {
                    op[0]  = v0;
                    op[16] = v1;
                } else {
                    const float mv = mask_val(mask, b2 * TT + t2);
                    op[0]  = (op[0]  + v0) * mv;
                    op[16] = (op[16] + v1) * mv;
                }
            }
        }
    }
}

// ---------------- fp32 lora1 (x-mix @ dw1, tanh), 16-row tiles ----------------
__global__ __launch_bounds__(256)
void lora1_kernel(const float* __restrict__ x, const float* __restrict__ mu,
                  const float* __restrict__ dw1, float* __restrict__ out,
                  const int dir)
{
    __shared__ float As[16][68];
    __shared__ float Bs[64][68];
    const int tid = threadIdx.x;
    const int rowbase = blockIdx.x << 4;

    const int arow = tid >> 4;
    const int akq  = (tid & 15) << 2;
    const int s  = rowbase + arow;
    const int bb = s >> 10, ts = s & (TT - 1);
    const int t  = dir ? (TT - 1 - ts) : ts;
    const int tp = dir ? (t + 1) : (t - 1);

    const int c0 = tid & 63;
    const int r4 = tid >> 6;

    float acc[4] = {0.f, 0.f, 0.f, 0.f};

    for (int k0 = 0; k0 < CC; k0 += 64) {
        {
            const int c = k0 + akq;
            const float4 xa = *reinterpret_cast<const float4*>(
                x + (size_t)(bb * TT + t) * CC + c);
            float4 xp = make_float4(0.f, 0.f, 0.f, 0.f);
            if (ts > 0)
                xp = *reinterpret_cast<const float4*>(
                    x + (size_t)(bb * TT + tp) * CC + c);
            const float4 m4 = *reinterpret_cast<const float4*>(mu + c);
            float4 va;
            va.x = fmaf(xp.x - xa.x, m4.x, xa.x);
            va.y = fmaf(xp.y - xa.y, m4.y, xa.y);
            va.z = fmaf(xp.z - xa.z, m4.z, xa.z);
            va.w = fmaf(xp.w - xa.w, m4.w, xa.w);
            *reinterpret_cast<float4*>(&As[arow][akq]) = va;
        }
        #pragma unroll
        for (int it = 0; it < 4; ++it) {
            const int c2 = tid + (it << 8);
            const int brow = c2 >> 4, bcol = (c2 & 15) << 2;
            *reinterpret_cast<float4*>(&Bs[brow][bcol]) =
                *reinterpret_cast<const float4*>(
                    dw1 + (size_t)(k0 + brow) * LR + bcol);
        }
        __syncthreads();
        #pragma unroll
        for (int k4 = 0; k4 < 16; ++k4) {
            float bv[4];
            #pragma unroll
            for (int q = 0; q < 4; ++q) bv[q] = Bs[(k4 << 2) + q][c0];
            #pragma unroll
            for (int i = 0; i < 4; ++i) {
                const float4 a4 = *reinterpret_cast<const float4*>(
                    &As[r4 + (i << 2)][k4 << 2]);
                acc[i] = fmaf(a4.x, bv[0], acc[i]);
                acc[i] = fmaf(a4.y, bv[1], acc[i]);
                acc[i] = fmaf(a4.z, bv[2], acc[i]);
                acc[i] = fmaf(a4.w, bv[3], acc[i]);
            }
        }
        __syncthreads();
    }
    #pragma unroll
    for (int i = 0; i < 4; ++i)
        out[(size_t)(rowbase + r4 + (i << 2)) * LR + c0] = tanhf(acc[i]);
}

// ---------------- fp32 GEMM (lora2: decay exp(-exp)) ----------------
__global__ __launch_bounds__(256)
void gemm_kernel(const float* __restrict__ Ap, const float* __restrict__ W,
                 const float* __restrict__ bias, float* __restrict__ out,
                 const int K, const int N)
{
    __shared__ float As[16][68];
    __shared__ float Bs[16][68];
    const int tid = threadIdx.x;
    const int rowbase = blockIdx.x << 6;
    const int colbase = blockIdx.y << 6;
    const int ty = tid >> 4, tx = tid & 15;
    const int am = tid >> 2;
    const int aq = tid & 3;
    const int s  = rowbase + am;
    const int bk = tid >> 4;
    const int bn = (tid & 15) << 2;

    float acc[4][4];
    #pragma unroll
    for (int i = 0; i < 4; ++i)
        #pragma unroll
        for (int j = 0; j < 4; ++j) acc[i][j] = 0.f;

    for (int k0 = 0; k0 < K; k0 += 16) {
        const float4 va = *reinterpret_cast<const float4*>(
            Ap + (size_t)s * K + k0 + (aq << 2));
        const float4 vb = *reinterpret_cast<const float4*>(
            W + (size_t)(k0 + bk) * N + colbase + bn);
        As[(aq << 2) + 0][am] = va.x;
        As[(aq << 2) + 1][am] = va.y;
        As[(aq << 2) + 2][am] = va.z;
        As[(aq << 2) + 3][am] = va.w;
        *reinterpret_cast<float4*>(&Bs[bk][bn]) = vb;
        __syncthreads();
        #pragma unroll
        for (int kk = 0; kk < 16; ++kk) {
            const float4 a  = *reinterpret_cast<const float4*>(&As[kk][ty << 2]);
            const float4 bv = *reinterpret_cast<const float4*>(&Bs[kk][tx << 2]);
            const float av[4]  = {a.x, a.y, a.z, a.w};
            const float bvv[4] = {bv.x, bv.y, bv.z, bv.w};
            #pragma unroll
            for (int i = 0; i < 4; ++i)
                #pragma unroll
                for (int j = 0; j < 4; ++j)
                    acc[i][j] = fmaf(av[i], bvv[j], acc[i][j]);
        }
        __syncthreads();
    }

    #pragma unroll
    for (int i = 0; i < 4; ++i) {
        const int srow = rowbase + (ty << 2) + i;
        const int ncol = colbase + (tx << 2);
        float v[4];
        #pragma unroll
        for (int j = 0; j < 4; ++j)
            v[j] = expf(-expf(acc[i][j] + bias[ncol + j]));
        *reinterpret_cast<float4*>(out + (size_t)srow * N + ncol) =
            make_float4(v[0], v[1], v[2], v[3]);
    }
}

// ---------------- chunked scan (A/B/C), round-6 forms ----------------
template<int L>
__global__ __launch_bounds__(64)
void scanA_kernel(const float* __restrict__ kbuf, const float* __restrict__ vbuf,
                  const float* __restrict__ wbuf,
                  float* __restrict__ SL, float* __restrict__ Pbuf)
{
    __shared__ float lk[L * DD], lw[L * DD], lv[L * DD];
    const int c = blockIdx.x, h = blockIdx.y, b = blockIdx.z;
    const int e = threadIdx.x;
    const int rowq = e >> 4;
    const int col  = (e & 15) << 2;

    const size_t gbase = (size_t)(b * TT + c * L) * CC + h * DD;
    #pragma unroll
    for (int r4 = 0; r4 < L / 4; ++r4) {
        const int row = (r4 << 2) + rowq;
        const size_t ga = gbase + (size_t)row * CC + col;
        *reinterpret_cast<float4*>(&lk[row * DD + col]) =
            *reinterpret_cast<const float4*>(kbuf + ga);
        *reinterpret_cast<float4*>(&lw[row * DD + col]) =
            *reinterpret_cast<const float4*>(wbuf + ga);
        *reinterpret_cast<float4*>(&lv[row * DD + col]) =
            *reinterpret_cast<const float4*>(vbuf + ga);
    }
    __syncthreads();

    float S[DD];
    #pragma unroll
    for (int d = 0; d < DD; ++d) S[d] = 0.f;
    float P = 1.f;

    for (int t = 0; t < L; ++t) {
        const float ve = lv[t * DD + e];
        P *= lw[t * DD + e];
        #pragma unroll
        for (int d4 = 0; d4 < 16; ++d4) {
            const float4 k4 = *reinterpret_cast<const float4*>(&lk[t * DD + (d4 << 2)]);
            const float4 w4 = *reinterpret_cast<const float4*>(&lw[t * DD + (d4 << 2)]);
            S[(d4 << 2) + 0] = fmaf(w4.x, S[(d4 << 2) + 0], k4.x * ve);
            S[(d4 << 2) + 1] = fmaf(w4.y, S[(d4 << 2) + 1], k4.y * ve);
            S[(d4 << 2) + 2] = fmaf(w4.z, S[(d4 << 2) + 2], k4.z * ve);
            S[(d4 << 2) + 3] = fmaf(w4.w, S[(d4 << 2) + 3], k4.w * ve);
        }
    }

    float* slot = SL + (size_t)((c * BBB + b) * HH + h) * DD * DD;
    #pragma unroll
    for (int d = 0; d < DD; ++d) slot[d * DD + e] = S[d];
    Pbuf[(size_t)((c * BBB + b) * HH + h) * DD + e] = P;
}

// Pass B: sequential over chunks, depth-1 register prefetch.
__global__ __launch_bounds__(64)
void scanB_kernel(float* __restrict__ SL, const float* __restrict__ Pbuf,
                  const int nch)
{
    const int h = blockIdx.x, b = blockIdx.y, dg = blockIdx.z;
    const int e = threadIdx.x;
    const size_t doff = (size_t)dg * 16 * DD;

    float S[16];
    #pragma unroll
    for (int i = 0; i < 16; ++i) S[i] = 0.f;

    float sl[16], pp[16];
    {
        const float* s0 = SL + (size_t)(b * HH + h) * DD * DD + doff;
        const float* p0 = Pbuf + (size_t)(b * HH + h) * DD + dg * 16;
        #pragma unroll
        for (int i = 0; i < 16; ++i) { sl[i] = s0[i * DD + e]; pp[i] = p0[i]; }
    }
    for (int c = 0; c < nch; ++c) {
        float sl2[16], pp2[16];
        if (c + 1 < nch) {
            const float* s1 = SL + (size_t)(((c + 1) * BBB + b) * HH + h) * DD * DD + doff;
            const float* p1 = Pbuf + (size_t)(((c + 1) * BBB + b) * HH + h) * DD + dg * 16;
            #pragma unroll
            for (int i = 0; i < 16; ++i) { sl2[i] = s1[i * DD + e]; pp2[i] = p1[i]; }
        }
        float* sc = SL + (size_t)((c * BBB + b) * HH + h) * DD * DD + doff;
        #pragma unroll
        for (int i = 0; i < 16; ++i) {
            S[i] = fmaf(pp[i], S[i], sl[i]);
            sc[i * DD + e] = S[i];
        }
        #pragma unroll
        for (int i = 0; i < 16; ++i) { sl[i] = sl2[i]; pp[i] = pp2[i]; }
    }
}

template<int L>
__global__ __launch_bounds__(64)
void scanC_kernel(const float* __restrict__ rbuf, const float* __restrict__ kbuf,
                  const float* __restrict__ vbuf, const float* __restrict__ wbuf,
                  const float* __restrict__ gbuf, const float* __restrict__ SL,
                  const float* __restrict__ u, const float* __restrict__ lnw,
                  const float* __restrict__ lnb, u16* __restrict__ zb,
                  const int dir)
{
    __shared__ float lr[L * DD], lk[L * DD], lw[L * DD];
    const int c = blockIdx.x, h = blockIdx.y, b = blockIdx.z;
    const int e = threadIdx.x;
    const int rowq = e >> 4;
    const int col  = (e & 15) << 2;

    const size_t gbase = (size_t)(b * TT + c * L) * CC + h * DD;
    #pragma unroll
    for (int r4 = 0; r4 < L / 4; ++r4) {
        const int row = (r4 << 2) + rowq;
        const size_t ga = gbase + (size_t)row * CC + col;
        *reinterpret_cast<float4*>(&lr[row * DD + col]) =
            *reinterpret_cast<const float4*>(rbuf + ga);
        *reinterpret_cast<float4*>(&lk[row * DD + col]) =
            *reinterpret_cast<const float4*>(kbuf + ga);
        *reinterpret_cast<float4*>(&lw[row * DD + col]) =
            *reinterpret_cast<const float4*>(wbuf + ga);
    }
    __syncthreads();

    const float ue = u[(size_t)(dir * HH + h) * DD + e];
    const float gw = lnw[dir * CC + h * DD + e];
    const float gb = lnb[dir * CC + h * DD + e];

    float S[DD];
    if (c == 0) {
        #pragma unroll
        for (int d = 0; d < DD; ++d) S[d] = 0.f;
    } else {
        const float* slot = SL + (size_t)(((c - 1) * BBB + b) * HH + h) * DD * DD;
        #pragma unroll
        for (int d = 0; d < DD; ++d) S[d] = slot[d * DD + e];
    }

    float ve = vbuf[gbase + e];
    float ge = gbuf[gbase + e];
    for (int t = 0; t < L; ++t) {
        float ve2 = 0.f, ge2 = 0.f;
        if (t + 1 < L) {
            ve2 = vbuf[gbase + (size_t)(t + 1) * CC + e];
            ge2 = gbuf[gbase + (size_t)(t + 1) * CC + e];
        }
        float coef = lr[t * DD + e] * ue * lk[t * DD + e];
        #pragma unroll
        for (int off = 32; off > 0; off >>= 1) coef += __shfl_xor(coef, off);

        float y0 = 0.f, y1 = 0.f, y2 = 0.f, y3 = 0.f;
        #pragma unroll
        for (int d4 = 0; d4 < 16; ++d4) {
            const float4 r4 = *reinterpret_cast<const float4*>(&lr[t * DD + (d4 << 2)]);
            const float4 k4 = *reinterpret_cast<const float4*>(&lk[t * DD + (d4 << 2)]);
            const float4 w4 = *reinterpret_cast<const float4*>(&lw[t * DD + (d4 << 2)]);
            y0 = fmaf(r4.x, S[(d4 << 2) + 0], y0);
            y1 = fmaf(r4.y, S[(d4 << 2) + 1], y1);
            y2 = fmaf(r4.z, S[(d4 << 2) + 2], y2);
            y3 = fmaf(r4.w, S[(d4 << 2) + 3], y3);
            S[(d4 << 2) + 0] = fmaf(w4.x, S[(d4 << 2) + 0], k4.x * ve);
            S[(d4 << 2) + 1] = fmaf(w4.y, S[(d4 << 2) + 1], k4.y * ve);
            S[(d4 << 2) + 2] = fmaf(w4.z, S[(d4 << 2) + 2], k4.z * ve);
            S[(d4 << 2) + 3] = fmaf(w4.w, S[(d4 << 2) + 3], k4.w * ve);
        }
        float y = ((y0 + y1) + (y2 + y3)) + coef * ve;

        float sum = y, sq = y * y;
        #pragma unroll
        for (int off = 32; off > 0; off >>= 1) {
            sum += __shfl_xor(sum, off);
            sq  += __shfl_xor(sq, off);
        }
        const float mean = sum * (1.f / 64.f);
        const float var  = fmaf(-mean, mean, sq * (1.f / 64.f));
        const float yn   = (y - mean) * rsqrtf(var + 1e-5f) * gw + gb;
        zb[gbase + (size_t)t * CC + e] = f2h(yn * ge);
        ve = ve2;
        ge = ge2;
    }
}

extern "C" void kernel_launch(void* const* d_in, const int* in_sizes, int n_in,
                              void* d_out, int out_size, void* d_ws, size_t ws_size,
                              hipStream_t stream)
{
    const float* x     = (const float*)d_in[0];
    const void*  mask  = d_in[1];
    const float* mu    = (const float*)d_in[2];
    const float* wbias = (const float*)d_in[3];
    const float* dw1   = (const float*)d_in[4];
    const float* dw2   = (const float*)d_in[5];
    const float* u     = (const float*)d_in[6];
    const float* Wr    = (const float*)d_in[7];
    const float* Wk    = (const float*)d_in[8];
    const float* Wv    = (const float*)d_in[9];
    const float* Wg    = (const float*)d_in[10];
    const float* Wo    = (const float*)d_in[11];
    const float* lnw   = (const float*)d_in[12];
    const float* lnb   = (const float*)d_in[13];
    float* out = (float*)d_out;

    float* ws = (float*)d_ws;
    const size_t NBT = (size_t)BT * CC;
    const size_t MUN = 2 * 5 * CC;

    auto need_bytes = [&](int nch, bool mixbuf) -> size_t {
        const size_t fl = 5 * NBT + (size_t)BT * LR
                        + (size_t)nch * BBB * HH * DD * DD
                        + (size_t)nch * BBB * HH * DD;
        const size_t hw = 2 * NBT + (size_t)10 * WSQ + MUN
                        + (mixbuf ? 4 * NBT : 0);
        return fl * 4 + hw * 2;
    };
    const bool mixbuf = ws_size >= need_bytes(16, true);
    const int nch = (ws_size >= need_bytes(64, mixbuf)) ? 64
                  : (ws_size >= need_bytes(32, mixbuf)) ? 32 : 16;

    float* rbuf  = ws;
    float* kbuf  = rbuf  + NBT;
    float* vbuf  = kbuf  + NBT;
    float* wwbuf = vbuf  + NBT;
    float* gbuf  = wwbuf + NBT;
    float* lora  = gbuf  + NBT;
    float* SL    = lora  + (size_t)BT * LR;
    float* Pbuf  = SL    + (size_t)nch * BBB * HH * DD * DD;
    u16*   zb    = (u16*)(Pbuf + (size_t)nch * BBB * HH * DD);
    u16*   xbb   = zb + NBT;
    u16*   wtb   = xbb + NBT;
    u16*   muh   = wtb + (size_t)10 * WSQ;
    u16*   mx0   = muh + MUN;          // 4 mixed A buffers (if mixbuf)
    u16*   mx1   = mx0 + NBT;
    u16*   mx2   = mx1 + NBT;
    u16*   mx3   = mx2 + NBT;

    TP10 tj;
    const float* Wlist[5] = {Wr, Wk, Wv, Wg, Wo};
    for (int dir = 0; dir < 2; ++dir)
        for (int i = 0; i < 5; ++i)
            tj.src[dir * 5 + i] = Wlist[i] + (size_t)dir * WSQ;
    transpose_conv<<<dim3(24, 24, 10), 256, 0, stream>>>(tj, wtb);
    convert_x<<<dim3(NBT / (8 * 256)), 256, 0, stream>>>(x, xbb);
    convert_mu<<<dim3((MUN + 255) / 256), 256, 0, stream>>>(mu, muh, (int)MUN);

    const dim3 gridBig(BT / 128, CC / 128, 4);
    const dim3 gridOut(BT / 128, CC / 128, 1);

    for (int dir = 0; dir < 2; ++dir) {
        const float* muD = mu + (size_t)dir * 5 * CC;
        const u16* wt = wtb + (size_t)dir * 5 * WSQ;

        GB pb;
        pb.Wt[0] = wt + 0 * WSQ; pb.out[0] = rbuf; pb.mu[0] = muD + 0 * CC; pb.act[0] = 0;
        pb.Wt[1] = wt + 1 * WSQ; pb.out[1] = kbuf; pb.mu[1] = muD + 1 * CC; pb.act[1] = 0;
        pb.Wt[2] = wt + 2 * WSQ; pb.out[2] = vbuf; pb.mu[2] = muD + 2 * CC; pb.act[2] = 0;
        pb.Wt[3] = wt + 3 * WSQ; pb.out[3] = gbuf; pb.mu[3] = muD + 4 * CC; pb.act[3] = 1;
        pb.Ab[0] = mx0; pb.Ab[1] = mx1; pb.Ab[2] = mx2; pb.Ab[3] = mx3;

        if (mixbuf) {
            mix4_kernel<<<dim3((int)(NBT / (8 * 256)), 4), 256, 0, stream>>>(
                xbb, muh + (size_t)dir * 5 * CC, mx0, mx1, mx2, mx3, dir);
            gemm_mfma_big<<<gridBig, 512, 0, stream>>>(pb, xbb, nullptr,
                                                       CC, CC, dir, 0);
        } else {
            gemm_mfma_big<<<gridBig, 512, 0, stream>>>(pb, xbb, nullptr,
                                                       CC, CC, dir, 1);
        }

        lora1_kernel<<<dim3(BT / 16), 256, 0, stream>>>(x, muD + 3 * CC,
                                                        dw1 + (size_t)dir * CC * LR,
                                                        lora, dir);
        gemm_kernel<<<dim3(BT / 64, CC / 64), 256, 0, stream>>>(
            lora, dw2 + (size_t)dir * LR * CC, wbias + (size_t)dir * CC,
            wwbuf, LR, CC);

        if (nch == 64) {
            scanA_kernel<16><<<dim3(64, HH, BBB), dim3(64), 0, stream>>>(
                kbuf, vbuf, wwbuf, SL, Pbuf);
            scanB_kernel<<<dim3(HH, BBB, 4), dim3(64), 0, stream>>>(SL, Pbuf, 64);
            scanC_kernel<16><<<dim3(64, HH, BBB), dim3(64), 0, stream>>>(
                rbuf, kbuf, vbuf, wwbuf, gbuf, SL, u, lnw, lnb, zb, dir);
        } else if (nch == 32) {
            scanA_kernel<32><<<dim3(32, HH, BBB), dim3(64), 0, stream>>>(
                kbuf, vbuf, wwbuf, SL, Pbuf);
            scanB_kernel<<<dim3(HH, BBB, 4), dim3(64), 0, stream>>>(SL, Pbuf, 32);
            scanC_kernel<32><<<dim3(32, HH, BBB), dim3(64), 0, stream>>>(
                rbuf, kbuf, vbuf, wwbuf, gbuf, SL, u, lnw, lnb, zb, dir);
        } else {
            scanA_kernel<64><<<dim3(16, HH, BBB), dim3(64), 0, stream>>>(
                kbuf, vbuf, wwbuf, SL, Pbuf);
            scanB_kernel<<<dim3(HH, BBB, 4), dim3(64), 0, stream>>>(SL, Pbuf, 16);
            scanC_kernel<64><<<dim3(16, HH, BBB), dim3(64), 0, stream>>>(
                rbuf, kbuf, vbuf, wwbuf, gbuf, SL, u, lnw, lnb, zb, dir);
        }

        GB po;
        po.Wt[0] = wt + 4 * WSQ; po.out[0] = out; po.mu[0] = nullptr;
        po.act[0] = (dir == 0) ? 4 : 5;
        po.Ab[0] = zb;
        po.Wt[1] = po.Wt[0]; po.out[1] = out; po.mu[1] = nullptr;
        po.act[1] = po.act[0]; po.Ab[1] = zb;
        po.Wt[2] = po.Wt[0]; po.out[2] = out; po.mu[2] = nullptr;
        po.act[2] = po.act[0]; po.Ab[2] = zb;
        po.Wt[3] = po.Wt[0]; po.out[3] = out; po.mu[3] = nullptr;
        po.act[3] = po.act[0]; po.Ab[3] = zb;
        gemm_mfma_big<<<gridOut, 512, 0, stream>>>(po, xbb, mask,
                                                   CC, CC, dir, 0);
    }
}